// Round 9
// baseline (168.186 us; speedup 1.0000x reference)
//
#include <hip/hip_runtime.h>

// ---------------------------------------------------------------------------
// GCN 3-layer forward on a static graph.
// R2: transforms -> LDS-tiled register-blocked SGEMM.
// R3: single-block scan -> 3-kernel parallel scan.
// R4: interleaved int2 CSR; aggregate unrolled x4; aggregate2+transform3 fused.
// R5: replicated global-atomic histograms -- NULL (device atomics ~25G/s).
// R6: zero global atomics -- LDS histograms + rank-scatter. 199->164us.
// R7: 64x64/TN=4 retile -- conflicts->0, occ 36%, dur WORSE. SGEMM is
//     LDS-read-issue bound: 4 SIMDs (128 FMA-lane/cyc) vs one LDS pipe
//     (~85B/cyc) -> need <=0.17 LDS floats per FMA-lane; tiles ingest 0.5.
// R8: scalar-W (SGPR) GEMM -- WORSE (53us, VALU 23%). VGPR=32 proved the
//     compiler refused the x-register file; W s_loads serialized on latency.
// R9: gemm_xreg -- x streamed global->VGPR (read once, broadcast-coalesced,
//     2-deep double-buffered xa/xb), W tiles in LDS read TN=4 (<=512B unique
//     per wave-read ~ 12cyc vs 64 FMA cyc) -> VALU-bound by construction.
// ---------------------------------------------------------------------------

#define NB 128     // edge groups == hist/scatter blocks
#define NW4 8192   // N/4 packed words (N = 32768)

typedef unsigned int uint32;

// Per-block src+dst histograms over all N nodes, packed u8 x4 per word.
__global__ __launch_bounds__(1024) void lds_hist_kernel(const int* __restrict__ src,
                                                        const int* __restrict__ dst,
                                                        uint32* __restrict__ part_src,
                                                        uint32* __restrict__ part_dst,
                                                        int e, int epb) {
  __shared__ uint32 hs[NW4];
  __shared__ uint32 hd[NW4];
  const int t = threadIdx.x;
  for (int w = t; w < NW4; w += 1024) {
    hs[w] = 0;
    hd[w] = 0;
  }
  __syncthreads();
  const int base = blockIdx.x * epb;
  for (int k = t; k < epb; k += 1024) {
    int i = base + k;
    if (i < e) {
      int s = src[i], d = dst[i];
      atomicAdd(&hs[s >> 2], 1u << ((s & 3) * 8));
      atomicAdd(&hd[d >> 2], 1u << ((d & 3) * 8));
    }
  }
  __syncthreads();
  uint32* ps = part_src + (size_t)blockIdx.x * NW4;
  uint32* pd = part_dst + (size_t)blockIdx.x * NW4;
  for (int w = t; w < NW4; w += 1024) {
    ps[w] = hs[w];
    pd[w] = hd[w];
  }
}

// Packed u32 adds across the NB partials, unpack -> norms + in_deg.
__global__ void reduce_norm_kernel(const uint32* __restrict__ part_src,
                                   const uint32* __restrict__ part_dst,
                                   float* __restrict__ norm_src, float* __restrict__ norm_dst,
                                   int* __restrict__ in_deg, int n4) {
  int w = blockIdx.x * blockDim.x + threadIdx.x;
  if (w >= n4) return;
  uint32 ss = 0, sd = 0;
  for (int r = 0; r < NB; ++r) {
    ss += part_src[(size_t)r * n4 + w];
    sd += part_dst[(size_t)r * n4 + w];
  }
#pragma unroll
  for (int j = 0; j < 4; ++j) {
    int v = w * 4 + j;
    int od = (ss >> (j * 8)) & 0xff;
    int id = (sd >> (j * 8)) & 0xff;
    norm_src[v] = 1.0f / sqrtf((float)max(od, 1));
    norm_dst[v] = 1.0f / sqrtf((float)max(id, 1));
    in_deg[v] = id;
  }
}

// --- parallel scan over in_deg -> row_ptr -----------------------------------
__global__ __launch_bounds__(256) void scan_partials_a(const int* __restrict__ deg,
                                                       int* __restrict__ block_sums, int n) {
  const int t = threadIdx.x;
  const int gid = blockIdx.x * 256 + t;
  int d = (gid < n) ? deg[gid] : 0;
#pragma unroll
  for (int off = 32; off > 0; off >>= 1) d += __shfl_down(d, off, 64);
  __shared__ int wsum[4];
  if ((t & 63) == 0) wsum[t >> 6] = d;
  __syncthreads();
  if (t == 0) block_sums[blockIdx.x] = wsum[0] + wsum[1] + wsum[2] + wsum[3];
}

__global__ __launch_bounds__(256) void scan_partials_b(int* __restrict__ block_sums,
                                                       int* __restrict__ block_offs, int nb) {
  __shared__ int sh[256];
  const int t = threadIdx.x;
  sh[t] = (t < nb) ? block_sums[t] : 0;
  __syncthreads();
  for (int off = 1; off < 256; off <<= 1) {
    int v = sh[t];
    int add = (t >= off) ? sh[t - off] : 0;
    __syncthreads();
    sh[t] = v + add;
    __syncthreads();
  }
  if (t < nb) block_offs[t] = (t > 0) ? sh[t - 1] : 0; // exclusive
}

__global__ __launch_bounds__(256) void scan_write(const int* __restrict__ deg,
                                                  const int* __restrict__ block_offs,
                                                  int* __restrict__ row_ptr, int n) {
  __shared__ int sh[256];
  const int t = threadIdx.x;
  const int gid = blockIdx.x * 256 + t;
  int d = (gid < n) ? deg[gid] : 0;
  sh[t] = d;
  __syncthreads();
  for (int off = 1; off < 256; off <<= 1) {
    int v = sh[t];
    int add = (t >= off) ? sh[t - off] : 0;
    __syncthreads();
    sh[t] = v + add;
    __syncthreads();
  }
  if (gid < n) {
    int excl = block_offs[blockIdx.x] + sh[t] - d;
    row_ptr[gid] = excl;
    if (gid == n - 1) row_ptr[n] = excl + d;
  }
}

// goff[r][v] = row_ptr[v] + sum_{r'<r} cnt[r'][v]
__global__ void group_offs_kernel(const uint32* __restrict__ part_dst,
                                  const int* __restrict__ row_ptr,
                                  int* __restrict__ goff, int n) {
  int v = blockIdx.x * blockDim.x + threadIdx.x;
  if (v >= n) return;
  int base = row_ptr[v];
  const int w = v >> 2;
  const int sh = (v & 3) * 8;
  const int n4 = n >> 2;
  for (int r = 0; r < NB; ++r) {
    goff[(size_t)r * n + v] = base;
    base += (part_dst[(size_t)r * n4 + w] >> sh) & 0xff;
  }
}

// Scatter with per-block LDS rank histogram -> unique positions, no global atomics.
__global__ __launch_bounds__(1024) void scatter_kernel(const int* __restrict__ src,
                                                       const int* __restrict__ dst,
                                                       const float* __restrict__ ew,
                                                       const int* __restrict__ goff,
                                                       int2* __restrict__ csr,
                                                       int n, int e, int epb) {
  __shared__ uint32 rk[NW4];
  const int t = threadIdx.x;
  for (int w = t; w < NW4; w += 1024) rk[w] = 0;
  __syncthreads();
  const int base = blockIdx.x * epb;
  const int* gof = goff + (size_t)blockIdx.x * n;
  for (int k = t; k < epb; k += 1024) {
    int i = base + k;
    if (i < e) {
      int d = dst[i];
      uint32 sh = (d & 3) * 8;
      uint32 old = atomicAdd(&rk[d >> 2], 1u << sh);
      int rank = (old >> sh) & 0xff;
      csr[gof[d] + rank] = make_int2(src[i], __float_as_int(ew[i]));
    }
  }
}

// ---------------------------------------------------------------------------
// gemm_xreg: ht = (x @ W) * norm_src[:,None]
// 256 threads; thread = (tcol, trow); owns TM contiguous rows x 4 cols.
// x: global -> VGPR float4 per k4-group, double-buffered (xa/xb), addresses
//    shared by all same-trow threads (coalesced broadcast), each byte read
//    exactly once per block. W: LDS tile [BK][BN], read as b128 at tcol*4
//    (<=512B unique per wave-read). Inner loop: pure v_fmac.
// ---------------------------------------------------------------------------
template <int K, int OUT, int TM>
__global__ __launch_bounds__(256) void gemm_xreg(const float* __restrict__ x,
                                                 const float* __restrict__ W,
                                                 const float* __restrict__ norm_src,
                                                 float* __restrict__ ht, int n) {
  constexpr int BN = OUT;
  constexpr int TCOL = BN / 4;
  constexpr int TROW = 256 / TCOL;
  constexpr int BM = TROW * TM;
  constexpr int BK = 64;
  static_assert(K % BK == 0 && BM * (256 / TROW) != 0, "shape");
  __shared__ float Ws[BK][BN];

  const int tid = threadIdx.x;
  const int tcol = tid % TCOL;
  const int trow = tid / TCOL;
  const int row0 = blockIdx.x * BM + trow * TM;

  float acc[TM][4];
#pragma unroll
  for (int i = 0; i < TM; ++i)
#pragma unroll
    for (int j = 0; j < 4; ++j) acc[i][j] = 0.f;

  float4 xa[TM], xb[TM];

#define LOADX(buf, kg)                                                                  \
  {                                                                                     \
    _Pragma("unroll") for (int i_ = 0; i_ < TM; ++i_) buf[i_] =                         \
        *reinterpret_cast<const float4*>(x + (size_t)(row0 + i_) * K + (kg));           \
  }
#define FMA4(buf, kbase)                                                                \
  {                                                                                     \
    _Pragma("unroll") for (int kk_ = 0; kk_ < 4; ++kk_) {                               \
      float4 bv_ = *reinterpret_cast<const float4*>(&Ws[(kbase) + kk_][tcol * 4]);      \
      _Pragma("unroll") for (int i_ = 0; i_ < TM; ++i_) {                               \
        float a_ = (&buf[i_].x)[kk_];                                                   \
        acc[i_][0] += a_ * bv_.x;                                                       \
        acc[i_][1] += a_ * bv_.y;                                                       \
        acc[i_][2] += a_ * bv_.z;                                                       \
        acc[i_][3] += a_ * bv_.w;                                                       \
      }                                                                                 \
    }                                                                                   \
  }

  LOADX(xa, 0);

#pragma unroll 1
  for (int k0 = 0; k0 < K; k0 += BK) {
    // stage W tile
    constexpr int NLD = BK * BN / 4 / 256;
#pragma unroll
    for (int p = 0; p < NLD; ++p) {
      int idx = p * 256 + tid;
      int kr = idx / (BN / 4);
      int c4 = idx % (BN / 4);
      *reinterpret_cast<float4*>(&Ws[kr][c4 * 4]) =
          *reinterpret_cast<const float4*>(W + (size_t)(k0 + kr) * OUT + c4 * 4);
    }
    __syncthreads();

#pragma unroll
    for (int q = 0; q < BK / 4; q += 2) {
      // prefetch next k4-group while computing current (xa)
      LOADX(xb, k0 + (q + 1) * 4);
      FMA4(xa, q * 4);
      // prefetch the group after (may cross into next BK chunk; clamp at K)
      int kg2 = k0 + (q + 2) * 4;
      kg2 = (kg2 < K) ? kg2 : (K - 4);
      LOADX(xa, kg2);
      FMA4(xb, q * 4 + 4);
    }
    __syncthreads();
  }
#undef LOADX
#undef FMA4

  // epilogue: fold norm_src per row, store float4
#pragma unroll
  for (int i = 0; i < TM; ++i) {
    const int row = row0 + i;
    const float ns = norm_src[row];
    float4 r = {acc[i][0] * ns, acc[i][1] * ns, acc[i][2] * ns, acc[i][3] * ns};
    *reinterpret_cast<float4*>(ht + (size_t)row * OUT + tcol * 4) = r;
  }
}

#define GATHER4(e, acc)                                                             \
  {                                                                                 \
    float w_ = __int_as_float(e.y);                                                 \
    float4 h_ = *reinterpret_cast<const float4*>(ht + (size_t)e.x * OUT + cg * 4);  \
    acc.x += w_ * h_.x;                                                             \
    acc.y += w_ * h_.y;                                                             \
    acc.z += w_ * h_.z;                                                             \
    acc.w += w_ * h_.w;                                                             \
  }

// out[v][col] = tanh( norm_dst[v] * sum_{e in CSR[v]} w_e * ht[src_e][col] + bias[col] )
template <int OUT>
__global__ void aggregate_kernel(const float* __restrict__ ht, const int* __restrict__ row_ptr,
                                 const int2* __restrict__ csr, const float* __restrict__ norm_dst,
                                 const float* __restrict__ bias, float* __restrict__ out, int n) {
  constexpr int LPN = OUT / 4;
  constexpr int NPB = 256 / LPN;
  const int tid = threadIdx.x;
  const int cg = tid % LPN;
  const int v = blockIdx.x * NPB + tid / LPN;
  if (v >= n) return;

  const int s0 = row_ptr[v];
  const int s1 = row_ptr[v + 1];
  float4 a0 = {0, 0, 0, 0}, a1 = {0, 0, 0, 0}, a2 = {0, 0, 0, 0}, a3 = {0, 0, 0, 0};
  int i = s0;
  for (; i + 4 <= s1; i += 4) {
    int2 e0 = csr[i], e1 = csr[i + 1], e2 = csr[i + 2], e3 = csr[i + 3];
    GATHER4(e0, a0);
    GATHER4(e1, a1);
    GATHER4(e2, a2);
    GATHER4(e3, a3);
  }
  for (; i < s1; ++i) {
    int2 e = csr[i];
    GATHER4(e, a0);
  }
  float nd = norm_dst[v];
  float4 b4 = *reinterpret_cast<const float4*>(bias + cg * 4);
  float4 r;
  r.x = tanhf((a0.x + a1.x + a2.x + a3.x) * nd + b4.x);
  r.y = tanhf((a0.y + a1.y + a2.y + a3.y) * nd + b4.y);
  r.z = tanhf((a0.z + a1.z + a2.z + a3.z) * nd + b4.z);
  r.w = tanhf((a0.w + a1.w + a2.w + a3.w) * nd + b4.w);
  *reinterpret_cast<float4*>(out + (size_t)v * OUT + cg * 4) = r;
}

// Layer-2 aggregate fused with layer-3 transform.
__global__ void aggregate2_fuse3(const float* __restrict__ ht, const int* __restrict__ row_ptr,
                                 const int2* __restrict__ csr, const float* __restrict__ norm_dst,
                                 const float* __restrict__ norm_src, const float* __restrict__ bias,
                                 const float* __restrict__ W3, float* __restrict__ ht3, int n) {
  constexpr int OUT = 64;
  constexpr int LPN = OUT / 4; // 16
  constexpr int NPB = 256 / LPN;
  const int tid = threadIdx.x;
  const int cg = tid % LPN;
  const int v = blockIdx.x * NPB + tid / LPN;
  if (v >= n) return;

  const int s0 = row_ptr[v];
  const int s1 = row_ptr[v + 1];
  float4 a0 = {0, 0, 0, 0}, a1 = {0, 0, 0, 0}, a2 = {0, 0, 0, 0}, a3 = {0, 0, 0, 0};
  int i = s0;
  for (; i + 4 <= s1; i += 4) {
    int2 e0 = csr[i], e1 = csr[i + 1], e2 = csr[i + 2], e3 = csr[i + 3];
    GATHER4(e0, a0);
    GATHER4(e1, a1);
    GATHER4(e2, a2);
    GATHER4(e3, a3);
  }
  for (; i < s1; ++i) {
    int2 e = csr[i];
    GATHER4(e, a0);
  }
  float nd = norm_dst[v];
  float4 b4 = *reinterpret_cast<const float4*>(bias + cg * 4);
  float ox = tanhf((a0.x + a1.x + a2.x + a3.x) * nd + b4.x);
  float oy = tanhf((a0.y + a1.y + a2.y + a3.y) * nd + b4.y);
  float oz = tanhf((a0.z + a1.z + a2.z + a3.z) * nd + b4.z);
  float ow = tanhf((a0.w + a1.w + a2.w + a3.w) * nd + b4.w);
  float4 w3 = *reinterpret_cast<const float4*>(W3 + cg * 4);
  float p = ox * w3.x + oy * w3.y + oz * w3.z + ow * w3.w;
#pragma unroll
  for (int m = 1; m < 16; m <<= 1) p += __shfl_xor(p, m, 64);
  if (cg == 0) ht3[v] = p * norm_src[v];
}

// Layer 3 aggregate: out[v] = norm_dst[v] * sum w_e*ht3[src_e] + b3 (no tanh)
__global__ void aggregate3_kernel(const float* __restrict__ ht3, const int* __restrict__ row_ptr,
                                  const int2* __restrict__ csr, const float* __restrict__ norm_dst,
                                  const float* __restrict__ b3, float* __restrict__ out, int n) {
  int v = blockIdx.x * blockDim.x + threadIdx.x;
  if (v >= n) return;
  const int s0 = row_ptr[v];
  const int s1 = row_ptr[v + 1];
  float p0 = 0.f, p1 = 0.f, p2 = 0.f, p3 = 0.f;
  int i = s0;
  for (; i + 4 <= s1; i += 4) {
    int2 e0 = csr[i], e1 = csr[i + 1], e2 = csr[i + 2], e3 = csr[i + 3];
    p0 += __int_as_float(e0.y) * ht3[e0.x];
    p1 += __int_as_float(e1.y) * ht3[e1.x];
    p2 += __int_as_float(e2.y) * ht3[e2.x];
    p3 += __int_as_float(e3.y) * ht3[e3.x];
  }
  for (; i < s1; ++i) {
    int2 e = csr[i];
    p0 += __int_as_float(e.y) * ht3[e.x];
  }
  out[v] = (p0 + p1 + p2 + p3) * norm_dst[v] + b3[0];
}

extern "C" void kernel_launch(void* const* d_in, const int* in_sizes, int n_in,
                              void* d_out, int out_size, void* d_ws, size_t ws_size,
                              hipStream_t stream) {
  const float* b_z = (const float*)d_in[0];
  const int* src = (const int*)d_in[1];
  const int* dst = (const int*)d_in[2];
  const float* ew = (const float*)d_in[3];
  const float* W1 = (const float*)d_in[4];
  const float* b1 = (const float*)d_in[5];
  const float* W2 = (const float*)d_in[6];
  const float* b2 = (const float*)d_in[7];
  const float* W3 = (const float*)d_in[8];
  const float* b3 = (const float*)d_in[9];

  const int N = in_sizes[0] / 256; // 32768
  const int E = in_sizes[1];       // 524288
  const int N4 = N / 4;
  const int epb = (E + NB - 1) / NB; // 4096

  char* ws = (char*)d_ws;
  size_t off = 0;
  auto alloc = [&](size_t bytes) -> void* {
    void* p = ws + off;
    off += (bytes + 255) & ~(size_t)255;
    return p;
  };

  uint32* part_src = (uint32*)alloc((size_t)NB * N4 * 4); // 4 MB
  uint32* part_dst = (uint32*)alloc((size_t)NB * N4 * 4); // 4 MB
  int* goff = (int*)alloc((size_t)NB * N * 4);            // 16 MB
  float* norm_src = (float*)alloc((size_t)N * 4);
  float* norm_dst = (float*)alloc((size_t)N * 4);
  int* in_deg = (int*)alloc((size_t)N * 4);
  int* row_ptr = (int*)alloc((size_t)(N + 1) * 4);
  int* block_sums = (int*)alloc(256 * 4);
  int* block_offs = (int*)alloc(256 * 4);
  int2* csr = (int2*)alloc((size_t)E * 8);
  float* HT = (float*)alloc((size_t)N * 128 * 4);   // ht1 / ht2 (reused)
  float* ACT1 = (float*)alloc((size_t)N * 128 * 4); // layer1 activation
  float* HT3 = (float*)alloc((size_t)N * 4);

  const int nBlocks = (N + 255) / 256; // 128

  lds_hist_kernel<<<NB, 1024, 0, stream>>>(src, dst, part_src, part_dst, E, epb);
  reduce_norm_kernel<<<(N4 + 255) / 256, 256, 0, stream>>>(part_src, part_dst, norm_src,
                                                           norm_dst, in_deg, N4);
  scan_partials_a<<<nBlocks, 256, 0, stream>>>(in_deg, block_sums, N);
  scan_partials_b<<<1, 256, 0, stream>>>(block_sums, block_offs, nBlocks);
  scan_write<<<nBlocks, 256, 0, stream>>>(in_deg, block_offs, row_ptr, N);
  group_offs_kernel<<<nBlocks, 256, 0, stream>>>(part_dst, row_ptr, goff, N);
  scatter_kernel<<<NB, 1024, 0, stream>>>(src, dst, ew, goff, csr, N, E, epb);

  // Layer 1: 256 -> 128, tanh. TM=8 -> BM=64, grid 512.
  gemm_xreg<256, 128, 8><<<N / 64, 256, 0, stream>>>(b_z, W1, norm_src, HT, N);
  aggregate_kernel<128><<<(N + 7) / 8, 256, 0, stream>>>(HT, row_ptr, csr, norm_dst, b1, ACT1, N);
  // Layer 2: 128 -> 64 (tanh) fused with layer-3 transform (64 -> 1). TM=4 -> BM=64.
  gemm_xreg<128, 64, 4><<<N / 64, 256, 0, stream>>>(ACT1, W2, norm_src, HT, N);
  aggregate2_fuse3<<<(N + 15) / 16, 256, 0, stream>>>(HT, row_ptr, csr, norm_dst, norm_src, b2,
                                                      W3, HT3, N);
  // Layer 3 aggregate: 1 col, no tanh
  aggregate3_kernel<<<nBlocks, 256, 0, stream>>>(HT3, row_ptr, csr, norm_dst, b3,
                                                 (float*)d_out, N);
}

// Round 10
// 141.544 us; speedup vs baseline: 1.1882x; 1.1882x over previous
//
#include <hip/hip_runtime.h>

// ---------------------------------------------------------------------------
// GCN 3-layer forward on a static graph.
// R2-R6: tiled SGEMM, parallel scan, int2 CSR, LDS histograms/rank-scatter.
// R7-R9 (all ~45us, VALU ~33%): f32 SGEMM on CDNA4 is structurally capped --
//     one LDS pipe (85B/cyc/CU) vs 4 SIMDs, and cold x-stream latency can't
//     be hidden at the occupancy the VGPR budget allows.
// R10: bf16 split-precision MFMA GEMM. x = xh+xl (bf16 pair), W pre-split+
//     transposed (wsplit kernel). acc += xh*wh + xh*wl + xl*wh in f32 MFMA
//     accumulators (xl*wl ~ 2^-18, dropped). Err ~1e-5 << 3.5e-4 threshold.
//     mfma_f32_16x16x32_bf16; A: row=lane&15,k=(lane>>4)*8+i; B mirrored;
//     D: col=lane&15,row=(lane>>4)*4+reg (m89-verified).
// ---------------------------------------------------------------------------

#define NB 128     // edge groups == hist/scatter blocks
#define NW4 8192   // N/4 packed words (N = 32768)

typedef unsigned int uint32;
typedef unsigned short ushort_t;
typedef __attribute__((ext_vector_type(8))) short bf16x8;
typedef __attribute__((ext_vector_type(4))) float f32x4;

__device__ inline ushort_t f2bf(float f) {
  uint32 u = __float_as_uint(f);
  u += 0x7fffu + ((u >> 16) & 1u);
  return (ushort_t)(u >> 16);
}
__device__ inline float bf2f(ushort_t h) { return __uint_as_float(((uint32)h) << 16); }

// --- preprocessing (unchanged from R6) --------------------------------------

__global__ __launch_bounds__(1024) void lds_hist_kernel(const int* __restrict__ src,
                                                        const int* __restrict__ dst,
                                                        uint32* __restrict__ part_src,
                                                        uint32* __restrict__ part_dst,
                                                        int e, int epb) {
  __shared__ uint32 hs[NW4];
  __shared__ uint32 hd[NW4];
  const int t = threadIdx.x;
  for (int w = t; w < NW4; w += 1024) {
    hs[w] = 0;
    hd[w] = 0;
  }
  __syncthreads();
  const int base = blockIdx.x * epb;
  for (int k = t; k < epb; k += 1024) {
    int i = base + k;
    if (i < e) {
      int s = src[i], d = dst[i];
      atomicAdd(&hs[s >> 2], 1u << ((s & 3) * 8));
      atomicAdd(&hd[d >> 2], 1u << ((d & 3) * 8));
    }
  }
  __syncthreads();
  uint32* ps = part_src + (size_t)blockIdx.x * NW4;
  uint32* pd = part_dst + (size_t)blockIdx.x * NW4;
  for (int w = t; w < NW4; w += 1024) {
    ps[w] = hs[w];
    pd[w] = hd[w];
  }
}

__global__ void reduce_norm_kernel(const uint32* __restrict__ part_src,
                                   const uint32* __restrict__ part_dst,
                                   float* __restrict__ norm_src, float* __restrict__ norm_dst,
                                   int* __restrict__ in_deg, int n4) {
  int w = blockIdx.x * blockDim.x + threadIdx.x;
  if (w >= n4) return;
  uint32 ss = 0, sd = 0;
  for (int r = 0; r < NB; ++r) {
    ss += part_src[(size_t)r * n4 + w];
    sd += part_dst[(size_t)r * n4 + w];
  }
#pragma unroll
  for (int j = 0; j < 4; ++j) {
    int v = w * 4 + j;
    int od = (ss >> (j * 8)) & 0xff;
    int id = (sd >> (j * 8)) & 0xff;
    norm_src[v] = 1.0f / sqrtf((float)max(od, 1));
    norm_dst[v] = 1.0f / sqrtf((float)max(id, 1));
    in_deg[v] = id;
  }
}

__global__ __launch_bounds__(256) void scan_partials_a(const int* __restrict__ deg,
                                                       int* __restrict__ block_sums, int n) {
  const int t = threadIdx.x;
  const int gid = blockIdx.x * 256 + t;
  int d = (gid < n) ? deg[gid] : 0;
#pragma unroll
  for (int off = 32; off > 0; off >>= 1) d += __shfl_down(d, off, 64);
  __shared__ int wsum[4];
  if ((t & 63) == 0) wsum[t >> 6] = d;
  __syncthreads();
  if (t == 0) block_sums[blockIdx.x] = wsum[0] + wsum[1] + wsum[2] + wsum[3];
}

__global__ __launch_bounds__(256) void scan_partials_b(int* __restrict__ block_sums,
                                                       int* __restrict__ block_offs, int nb) {
  __shared__ int sh[256];
  const int t = threadIdx.x;
  sh[t] = (t < nb) ? block_sums[t] : 0;
  __syncthreads();
  for (int off = 1; off < 256; off <<= 1) {
    int v = sh[t];
    int add = (t >= off) ? sh[t - off] : 0;
    __syncthreads();
    sh[t] = v + add;
    __syncthreads();
  }
  if (t < nb) block_offs[t] = (t > 0) ? sh[t - 1] : 0; // exclusive
}

__global__ __launch_bounds__(256) void scan_write(const int* __restrict__ deg,
                                                  const int* __restrict__ block_offs,
                                                  int* __restrict__ row_ptr, int n) {
  __shared__ int sh[256];
  const int t = threadIdx.x;
  const int gid = blockIdx.x * 256 + t;
  int d = (gid < n) ? deg[gid] : 0;
  sh[t] = d;
  __syncthreads();
  for (int off = 1; off < 256; off <<= 1) {
    int v = sh[t];
    int add = (t >= off) ? sh[t - off] : 0;
    __syncthreads();
    sh[t] = v + add;
    __syncthreads();
  }
  if (gid < n) {
    int excl = block_offs[blockIdx.x] + sh[t] - d;
    row_ptr[gid] = excl;
    if (gid == n - 1) row_ptr[n] = excl + d;
  }
}

__global__ void group_offs_kernel(const uint32* __restrict__ part_dst,
                                  const int* __restrict__ row_ptr,
                                  int* __restrict__ goff, int n) {
  int v = blockIdx.x * blockDim.x + threadIdx.x;
  if (v >= n) return;
  int base = row_ptr[v];
  const int w = v >> 2;
  const int sh = (v & 3) * 8;
  const int n4 = n >> 2;
  for (int r = 0; r < NB; ++r) {
    goff[(size_t)r * n + v] = base;
    base += (part_dst[(size_t)r * n4 + w] >> sh) & 0xff;
  }
}

__global__ __launch_bounds__(1024) void scatter_kernel(const int* __restrict__ src,
                                                       const int* __restrict__ dst,
                                                       const float* __restrict__ ew,
                                                       const int* __restrict__ goff,
                                                       int2* __restrict__ csr,
                                                       int n, int e, int epb) {
  __shared__ uint32 rk[NW4];
  const int t = threadIdx.x;
  for (int w = t; w < NW4; w += 1024) rk[w] = 0;
  __syncthreads();
  const int base = blockIdx.x * epb;
  const int* gof = goff + (size_t)blockIdx.x * n;
  for (int k = t; k < epb; k += 1024) {
    int i = base + k;
    if (i < e) {
      int d = dst[i];
      uint32 sh = (d & 3) * 8;
      uint32 old = atomicAdd(&rk[d >> 2], 1u << sh);
      int rank = (old >> sh) & 0xff;
      csr[gof[d] + rank] = make_int2(src[i], __float_as_int(ew[i]));
    }
  }
}

// --- W pre-split: W[k][c] -> WhT[c][k], WlT[c][k] (bf16 hi/lo) --------------
__global__ void wsplit_kernel(const float* __restrict__ W, ushort_t* __restrict__ WhT,
                              ushort_t* __restrict__ WlT, int K, int OUT) {
  int i = blockIdx.x * blockDim.x + threadIdx.x;
  if (i >= K * OUT) return;
  int k = i / OUT, c = i % OUT;
  float f = W[i];
  ushort_t h = f2bf(f);
  ushort_t l = f2bf(f - bf2f(h));
  WhT[(size_t)c * K + k] = h;
  WlT[(size_t)c * K + k] = l;
}

// ---------------------------------------------------------------------------
// bf16-split MFMA GEMM: ht = (x @ W) * norm_src[:,None]
// Block: 256 thr = 4 waves (2x2). Wave tile: 32 rows x OUT/2 cols.
// Per 64-k chunk: stage x (f32->bf16 h/l) and WT (pre-split) to LDS; then
// 2 k-slices of 32 with 3 MFMAs per (row-tile, col-tile): hh, hl, lh.
// ---------------------------------------------------------------------------
template <int K, int OUT>
__global__ __launch_bounds__(256) void gemm_mfma(const float* __restrict__ x,
                                                 const ushort_t* __restrict__ WhT,
                                                 const ushort_t* __restrict__ WlT,
                                                 const float* __restrict__ norm_src,
                                                 float* __restrict__ ht, int n) {
  constexpr int BK = 64, KP = BK + 8; // 16B-aligned padded row
  constexpr int NCT = OUT / 32;       // col-tiles per wave (L1: 4, L2: 2)
  __shared__ ushort_t Xh[64][KP], Xl[64][KP];
  __shared__ ushort_t Wh[OUT][KP], Wl[OUT][KP];

  const int tid = threadIdx.x;
  const int wv = tid >> 6;
  const int lane = tid & 63;
  const int wr = wv >> 1; // row half (32 rows)
  const int wc = wv & 1;  // col half (OUT/2 cols)
  const int row0 = blockIdx.x * 64;
  const int fr = lane & 15; // frag row (A) / col (B)
  const int fg = lane >> 4; // k-group

  f32x4 acc[2][NCT];
#pragma unroll
  for (int i = 0; i < 2; ++i)
#pragma unroll
    for (int j = 0; j < NCT; ++j) acc[i][j] = (f32x4){0.f, 0.f, 0.f, 0.f};

#pragma unroll 1
  for (int k0 = 0; k0 < K; k0 += BK) {
    __syncthreads(); // protect LDS from previous iteration's readers
    // stage x chunk (64 rows x 64 k), converting f32 -> bf16 hi/lo
#pragma unroll
    for (int p = 0; p < 4; ++p) {
      int idx = p * 256 + tid;
      int r = idx >> 4, c4 = idx & 15;
      float4 v = *reinterpret_cast<const float4*>(x + (size_t)(row0 + r) * K + k0 + c4 * 4);
      ushort4 h, l;
      h.x = f2bf(v.x); l.x = f2bf(v.x - bf2f(h.x));
      h.y = f2bf(v.y); l.y = f2bf(v.y - bf2f(h.y));
      h.z = f2bf(v.z); l.z = f2bf(v.z - bf2f(h.z));
      h.w = f2bf(v.w); l.w = f2bf(v.w - bf2f(h.w));
      *reinterpret_cast<ushort4*>(&Xh[r][c4 * 4]) = h;
      *reinterpret_cast<ushort4*>(&Xl[r][c4 * 4]) = l;
    }
    // stage W chunk (OUT cols x 64 k, pre-split/transposed in global)
#pragma unroll
    for (int p = 0; p < OUT * 16 / 256; ++p) {
      int idx = p * 256 + tid;
      int c = idx >> 4, k4 = idx & 15;
      *reinterpret_cast<ushort4*>(&Wh[c][k4 * 4]) =
          *reinterpret_cast<const ushort4*>(WhT + (size_t)c * K + k0 + k4 * 4);
      *reinterpret_cast<ushort4*>(&Wl[c][k4 * 4]) =
          *reinterpret_cast<const ushort4*>(WlT + (size_t)c * K + k0 + k4 * 4);
    }
    __syncthreads();

#pragma unroll
    for (int s = 0; s < 2; ++s) { // two 32-k slices
      const int kk = s * 32 + fg * 8;
      bf16x8 ah[2], al[2];
#pragma unroll
      for (int i = 0; i < 2; ++i) {
        int r = wr * 32 + i * 16 + fr;
        ah[i] = *reinterpret_cast<const bf16x8*>(&Xh[r][kk]);
        al[i] = *reinterpret_cast<const bf16x8*>(&Xl[r][kk]);
      }
#pragma unroll
      for (int j = 0; j < NCT; ++j) {
        int c = wc * (OUT / 2) + j * 16 + fr;
        bf16x8 bh = *reinterpret_cast<const bf16x8*>(&Wh[c][kk]);
        bf16x8 bl = *reinterpret_cast<const bf16x8*>(&Wl[c][kk]);
#pragma unroll
        for (int i = 0; i < 2; ++i) {
          acc[i][j] = __builtin_amdgcn_mfma_f32_16x16x32_bf16(ah[i], bh, acc[i][j], 0, 0, 0);
          acc[i][j] = __builtin_amdgcn_mfma_f32_16x16x32_bf16(ah[i], bl, acc[i][j], 0, 0, 0);
          acc[i][j] = __builtin_amdgcn_mfma_f32_16x16x32_bf16(al[i], bh, acc[i][j], 0, 0, 0);
        }
      }
    }
  }

  // epilogue: D col=lane&15, row=(lane>>4)*4+reg (m89); fold norm_src
#pragma unroll
  for (int i = 0; i < 2; ++i) {
#pragma unroll
    for (int q = 0; q < 4; ++q) {
      int row = row0 + wr * 32 + i * 16 + fg * 4 + q;
      float ns = norm_src[row];
#pragma unroll
      for (int j = 0; j < NCT; ++j) {
        int col = wc * (OUT / 2) + j * 16 + fr;
        ht[(size_t)row * OUT + col] = acc[i][j][q] * ns;
      }
    }
  }
}

#define GATHER4(e, acc)                                                             \
  {                                                                                 \
    float w_ = __int_as_float(e.y);                                                 \
    float4 h_ = *reinterpret_cast<const float4*>(ht + (size_t)e.x * OUT + cg * 4);  \
    acc.x += w_ * h_.x;                                                             \
    acc.y += w_ * h_.y;                                                             \
    acc.z += w_ * h_.z;                                                             \
    acc.w += w_ * h_.w;                                                             \
  }

// out[v][col] = tanh( norm_dst[v] * sum_{e in CSR[v]} w_e * ht[src_e][col] + bias[col] )
template <int OUT>
__global__ void aggregate_kernel(const float* __restrict__ ht, const int* __restrict__ row_ptr,
                                 const int2* __restrict__ csr, const float* __restrict__ norm_dst,
                                 const float* __restrict__ bias, float* __restrict__ out, int n) {
  constexpr int LPN = OUT / 4;
  constexpr int NPB = 256 / LPN;
  const int tid = threadIdx.x;
  const int cg = tid % LPN;
  const int v = blockIdx.x * NPB + tid / LPN;
  if (v >= n) return;

  const int s0 = row_ptr[v];
  const int s1 = row_ptr[v + 1];
  float4 a0 = {0, 0, 0, 0}, a1 = {0, 0, 0, 0}, a2 = {0, 0, 0, 0}, a3 = {0, 0, 0, 0};
  int i = s0;
  for (; i + 4 <= s1; i += 4) {
    int2 e0 = csr[i], e1 = csr[i + 1], e2 = csr[i + 2], e3 = csr[i + 3];
    GATHER4(e0, a0);
    GATHER4(e1, a1);
    GATHER4(e2, a2);
    GATHER4(e3, a3);
  }
  for (; i < s1; ++i) {
    int2 e = csr[i];
    GATHER4(e, a0);
  }
  float nd = norm_dst[v];
  float4 b4 = *reinterpret_cast<const float4*>(bias + cg * 4);
  float4 r;
  r.x = tanhf((a0.x + a1.x + a2.x + a3.x) * nd + b4.x);
  r.y = tanhf((a0.y + a1.y + a2.y + a3.y) * nd + b4.y);
  r.z = tanhf((a0.z + a1.z + a2.z + a3.z) * nd + b4.z);
  r.w = tanhf((a0.w + a1.w + a2.w + a3.w) * nd + b4.w);
  *reinterpret_cast<float4*>(out + (size_t)v * OUT + cg * 4) = r;
}

// Layer-2 aggregate fused with layer-3 transform.
__global__ void aggregate2_fuse3(const float* __restrict__ ht, const int* __restrict__ row_ptr,
                                 const int2* __restrict__ csr, const float* __restrict__ norm_dst,
                                 const float* __restrict__ norm_src, const float* __restrict__ bias,
                                 const float* __restrict__ W3, float* __restrict__ ht3, int n) {
  constexpr int OUT = 64;
  constexpr int LPN = OUT / 4; // 16
  constexpr int NPB = 256 / LPN;
  const int tid = threadIdx.x;
  const int cg = tid % LPN;
  const int v = blockIdx.x * NPB + tid / LPN;
  if (v >= n) return;

  const int s0 = row_ptr[v];
  const int s1 = row_ptr[v + 1];
  float4 a0 = {0, 0, 0, 0}, a1 = {0, 0, 0, 0}, a2 = {0, 0, 0, 0}, a3 = {0, 0, 0, 0};
  int i = s0;
  for (; i + 4 <= s1; i += 4) {
    int2 e0 = csr[i], e1 = csr[i + 1], e2 = csr[i + 2], e3 = csr[i + 3];
    GATHER4(e0, a0);
    GATHER4(e1, a1);
    GATHER4(e2, a2);
    GATHER4(e3, a3);
  }
  for (; i < s1; ++i) {
    int2 e = csr[i];
    GATHER4(e, a0);
  }
  float nd = norm_dst[v];
  float4 b4 = *reinterpret_cast<const float4*>(bias + cg * 4);
  float ox = tanhf((a0.x + a1.x + a2.x + a3.x) * nd + b4.x);
  float oy = tanhf((a0.y + a1.y + a2.y + a3.y) * nd + b4.y);
  float oz = tanhf((a0.z + a1.z + a2.z + a3.z) * nd + b4.z);
  float ow = tanhf((a0.w + a1.w + a2.w + a3.w) * nd + b4.w);
  float4 w3 = *reinterpret_cast<const float4*>(W3 + cg * 4);
  float p = ox * w3.x + oy * w3.y + oz * w3.z + ow * w3.w;
#pragma unroll
  for (int m = 1; m < 16; m <<= 1) p += __shfl_xor(p, m, 64);
  if (cg == 0) ht3[v] = p * norm_src[v];
}

// Layer 3 aggregate: out[v] = norm_dst[v] * sum w_e*ht3[src_e] + b3 (no tanh)
__global__ void aggregate3_kernel(const float* __restrict__ ht3, const int* __restrict__ row_ptr,
                                  const int2* __restrict__ csr, const float* __restrict__ norm_dst,
                                  const float* __restrict__ b3, float* __restrict__ out, int n) {
  int v = blockIdx.x * blockDim.x + threadIdx.x;
  if (v >= n) return;
  const int s0 = row_ptr[v];
  const int s1 = row_ptr[v + 1];
  float p0 = 0.f, p1 = 0.f, p2 = 0.f, p3 = 0.f;
  int i = s0;
  for (; i + 4 <= s1; i += 4) {
    int2 e0 = csr[i], e1 = csr[i + 1], e2 = csr[i + 2], e3 = csr[i + 3];
    p0 += __int_as_float(e0.y) * ht3[e0.x];
    p1 += __int_as_float(e1.y) * ht3[e1.x];
    p2 += __int_as_float(e2.y) * ht3[e2.x];
    p3 += __int_as_float(e3.y) * ht3[e3.x];
  }
  for (; i < s1; ++i) {
    int2 e = csr[i];
    p0 += __int_as_float(e.y) * ht3[e.x];
  }
  out[v] = (p0 + p1 + p2 + p3) * norm_dst[v] + b3[0];
}

extern "C" void kernel_launch(void* const* d_in, const int* in_sizes, int n_in,
                              void* d_out, int out_size, void* d_ws, size_t ws_size,
                              hipStream_t stream) {
  const float* b_z = (const float*)d_in[0];
  const int* src = (const int*)d_in[1];
  const int* dst = (const int*)d_in[2];
  const float* ew = (const float*)d_in[3];
  const float* W1 = (const float*)d_in[4];
  const float* b1 = (const float*)d_in[5];
  const float* W2 = (const float*)d_in[6];
  const float* b2 = (const float*)d_in[7];
  const float* W3 = (const float*)d_in[8];
  const float* b3 = (const float*)d_in[9];

  const int N = in_sizes[0] / 256; // 32768
  const int E = in_sizes[1];       // 524288
  const int N4 = N / 4;
  const int epb = (E + NB - 1) / NB; // 4096

  char* ws = (char*)d_ws;
  size_t off = 0;
  auto alloc = [&](size_t bytes) -> void* {
    void* p = ws + off;
    off += (bytes + 255) & ~(size_t)255;
    return p;
  };

  uint32* part_src = (uint32*)alloc((size_t)NB * N4 * 4); // 4 MB
  uint32* part_dst = (uint32*)alloc((size_t)NB * N4 * 4); // 4 MB
  int* goff = (int*)alloc((size_t)NB * N * 4);            // 16 MB
  float* norm_src = (float*)alloc((size_t)N * 4);
  float* norm_dst = (float*)alloc((size_t)N * 4);
  int* in_deg = (int*)alloc((size_t)N * 4);
  int* row_ptr = (int*)alloc((size_t)(N + 1) * 4);
  int* block_sums = (int*)alloc(256 * 4);
  int* block_offs = (int*)alloc(256 * 4);
  int2* csr = (int2*)alloc((size_t)E * 8);
  float* HT = (float*)alloc((size_t)N * 128 * 4);   // ht1 / ht2 (reused)
  float* ACT1 = (float*)alloc((size_t)N * 128 * 4); // layer1 activation
  float* HT3 = (float*)alloc((size_t)N * 4);
  ushort_t* WhT1 = (ushort_t*)alloc((size_t)256 * 128 * 2);
  ushort_t* WlT1 = (ushort_t*)alloc((size_t)256 * 128 * 2);
  ushort_t* WhT2 = (ushort_t*)alloc((size_t)128 * 64 * 2);
  ushort_t* WlT2 = (ushort_t*)alloc((size_t)128 * 64 * 2);

  const int nBlocks = (N + 255) / 256; // 128

  lds_hist_kernel<<<NB, 1024, 0, stream>>>(src, dst, part_src, part_dst, E, epb);
  reduce_norm_kernel<<<(N4 + 255) / 256, 256, 0, stream>>>(part_src, part_dst, norm_src,
                                                           norm_dst, in_deg, N4);
  scan_partials_a<<<nBlocks, 256, 0, stream>>>(in_deg, block_sums, N);
  scan_partials_b<<<1, 256, 0, stream>>>(block_sums, block_offs, nBlocks);
  scan_write<<<nBlocks, 256, 0, stream>>>(in_deg, block_offs, row_ptr, N);
  group_offs_kernel<<<nBlocks, 256, 0, stream>>>(part_dst, row_ptr, goff, N);
  scatter_kernel<<<NB, 1024, 0, stream>>>(src, dst, ew, goff, csr, N, E, epb);
  wsplit_kernel<<<(256 * 128 + 255) / 256, 256, 0, stream>>>(W1, WhT1, WlT1, 256, 128);
  wsplit_kernel<<<(128 * 64 + 255) / 256, 256, 0, stream>>>(W2, WhT2, WlT2, 128, 64);

  // Layer 1: 256 -> 128, tanh
  gemm_mfma<256, 128><<<N / 64, 256, 0, stream>>>(b_z, WhT1, WlT1, norm_src, HT, N);
  aggregate_kernel<128><<<(N + 7) / 8, 256, 0, stream>>>(HT, row_ptr, csr, norm_dst, b1, ACT1, N);
  // Layer 2: 128 -> 64 (tanh) fused with layer-3 transform (64 -> 1)
  gemm_mfma<128, 64><<<N / 64, 256, 0, stream>>>(ACT1, WhT2, WlT2, norm_src, HT, N);
  aggregate2_fuse3<<<(N + 15) / 16, 256, 0, stream>>>(HT, row_ptr, csr, norm_dst, norm_src, b2,
                                                      W3, HT3, N);
  // Layer 3 aggregate: 1 col, no tanh
  aggregate3_kernel<<<nBlocks, 256, 0, stream>>>(HT3, row_ptr, csr, norm_dst, b3,
                                                 (float*)d_out, N);
}

// Round 11
// 123.952 us; speedup vs baseline: 1.3569x; 1.1419x over previous
//
#include <hip/hip_runtime.h>

// ---------------------------------------------------------------------------
// GCN 3-layer forward on a static graph.
// R2-R6: tiled SGEMM, parallel scan, int2 CSR, LDS histograms/rank-scatter.
// R7-R9 (~45us, VALU ~33%): f32 SGEMM structurally capped (one LDS pipe vs
//     4 SIMDs; cold-stream latency vs VGPR-limited occupancy).
// R10: bf16 split-precision MFMA GEMM (xh*wh+xh*wl+xl*wh in f32 acc):
//     168->141.5us, absmax unchanged (3e-5, fp32-reorder noise level).
// R11: HT (aggregate gather operand) stored bf16: gather traffic 268+134MB ->
//     134+67MB, HT writes halved. ACT1 (gemm2 input) stays f32 for the hi/lo
//     split. Predicted absmax ~1-2.5e-4 (vs 3.49e-4 threshold).
// ---------------------------------------------------------------------------

#define NB 128     // edge groups == hist/scatter blocks
#define NW4 8192   // N/4 packed words (N = 32768)

typedef unsigned int uint32;
typedef unsigned short ushort_t;
typedef __attribute__((ext_vector_type(8))) short bf16x8;
typedef __attribute__((ext_vector_type(4))) float f32x4;

__device__ inline ushort_t f2bf(float f) {
  uint32 u = __float_as_uint(f);
  u += 0x7fffu + ((u >> 16) & 1u);
  return (ushort_t)(u >> 16);
}
__device__ inline float bf2f(ushort_t h) { return __uint_as_float(((uint32)h) << 16); }

// --- preprocessing (unchanged from R6) --------------------------------------

__global__ __launch_bounds__(1024) void lds_hist_kernel(const int* __restrict__ src,
                                                        const int* __restrict__ dst,
                                                        uint32* __restrict__ part_src,
                                                        uint32* __restrict__ part_dst,
                                                        int e, int epb) {
  __shared__ uint32 hs[NW4];
  __shared__ uint32 hd[NW4];
  const int t = threadIdx.x;
  for (int w = t; w < NW4; w += 1024) {
    hs[w] = 0;
    hd[w] = 0;
  }
  __syncthreads();
  const int base = blockIdx.x * epb;
  for (int k = t; k < epb; k += 1024) {
    int i = base + k;
    if (i < e) {
      int s = src[i], d = dst[i];
      atomicAdd(&hs[s >> 2], 1u << ((s & 3) * 8));
      atomicAdd(&hd[d >> 2], 1u << ((d & 3) * 8));
    }
  }
  __syncthreads();
  uint32* ps = part_src + (size_t)blockIdx.x * NW4;
  uint32* pd = part_dst + (size_t)blockIdx.x * NW4;
  for (int w = t; w < NW4; w += 1024) {
    ps[w] = hs[w];
    pd[w] = hd[w];
  }
}

__global__ void reduce_norm_kernel(const uint32* __restrict__ part_src,
                                   const uint32* __restrict__ part_dst,
                                   float* __restrict__ norm_src, float* __restrict__ norm_dst,
                                   int* __restrict__ in_deg, int n4) {
  int w = blockIdx.x * blockDim.x + threadIdx.x;
  if (w >= n4) return;
  uint32 ss = 0, sd = 0;
  for (int r = 0; r < NB; ++r) {
    ss += part_src[(size_t)r * n4 + w];
    sd += part_dst[(size_t)r * n4 + w];
  }
#pragma unroll
  for (int j = 0; j < 4; ++j) {
    int v = w * 4 + j;
    int od = (ss >> (j * 8)) & 0xff;
    int id = (sd >> (j * 8)) & 0xff;
    norm_src[v] = 1.0f / sqrtf((float)max(od, 1));
    norm_dst[v] = 1.0f / sqrtf((float)max(id, 1));
    in_deg[v] = id;
  }
}

__global__ __launch_bounds__(256) void scan_partials_a(const int* __restrict__ deg,
                                                       int* __restrict__ block_sums, int n) {
  const int t = threadIdx.x;
  const int gid = blockIdx.x * 256 + t;
  int d = (gid < n) ? deg[gid] : 0;
#pragma unroll
  for (int off = 32; off > 0; off >>= 1) d += __shfl_down(d, off, 64);
  __shared__ int wsum[4];
  if ((t & 63) == 0) wsum[t >> 6] = d;
  __syncthreads();
  if (t == 0) block_sums[blockIdx.x] = wsum[0] + wsum[1] + wsum[2] + wsum[3];
}

__global__ __launch_bounds__(256) void scan_partials_b(int* __restrict__ block_sums,
                                                       int* __restrict__ block_offs, int nb) {
  __shared__ int sh[256];
  const int t = threadIdx.x;
  sh[t] = (t < nb) ? block_sums[t] : 0;
  __syncthreads();
  for (int off = 1; off < 256; off <<= 1) {
    int v = sh[t];
    int add = (t >= off) ? sh[t - off] : 0;
    __syncthreads();
    sh[t] = v + add;
    __syncthreads();
  }
  if (t < nb) block_offs[t] = (t > 0) ? sh[t - 1] : 0; // exclusive
}

__global__ __launch_bounds__(256) void scan_write(const int* __restrict__ deg,
                                                  const int* __restrict__ block_offs,
                                                  int* __restrict__ row_ptr, int n) {
  __shared__ int sh[256];
  const int t = threadIdx.x;
  const int gid = blockIdx.x * 256 + t;
  int d = (gid < n) ? deg[gid] : 0;
  sh[t] = d;
  __syncthreads();
  for (int off = 1; off < 256; off <<= 1) {
    int v = sh[t];
    int add = (t >= off) ? sh[t - off] : 0;
    __syncthreads();
    sh[t] = v + add;
    __syncthreads();
  }
  if (gid < n) {
    int excl = block_offs[blockIdx.x] + sh[t] - d;
    row_ptr[gid] = excl;
    if (gid == n - 1) row_ptr[n] = excl + d;
  }
}

__global__ void group_offs_kernel(const uint32* __restrict__ part_dst,
                                  const int* __restrict__ row_ptr,
                                  int* __restrict__ goff, int n) {
  int v = blockIdx.x * blockDim.x + threadIdx.x;
  if (v >= n) return;
  int base = row_ptr[v];
  const int w = v >> 2;
  const int sh = (v & 3) * 8;
  const int n4 = n >> 2;
  for (int r = 0; r < NB; ++r) {
    goff[(size_t)r * n + v] = base;
    base += (part_dst[(size_t)r * n4 + w] >> sh) & 0xff;
  }
}

__global__ __launch_bounds__(1024) void scatter_kernel(const int* __restrict__ src,
                                                       const int* __restrict__ dst,
                                                       const float* __restrict__ ew,
                                                       const int* __restrict__ goff,
                                                       int2* __restrict__ csr,
                                                       int n, int e, int epb) {
  __shared__ uint32 rk[NW4];
  const int t = threadIdx.x;
  for (int w = t; w < NW4; w += 1024) rk[w] = 0;
  __syncthreads();
  const int base = blockIdx.x * epb;
  const int* gof = goff + (size_t)blockIdx.x * n;
  for (int k = t; k < epb; k += 1024) {
    int i = base + k;
    if (i < e) {
      int d = dst[i];
      uint32 sh = (d & 3) * 8;
      uint32 old = atomicAdd(&rk[d >> 2], 1u << sh);
      int rank = (old >> sh) & 0xff;
      csr[gof[d] + rank] = make_int2(src[i], __float_as_int(ew[i]));
    }
  }
}

// --- W pre-split: W[k][c] -> WhT[c][k], WlT[c][k] (bf16 hi/lo) --------------
__global__ void wsplit_kernel(const float* __restrict__ W, ushort_t* __restrict__ WhT,
                              ushort_t* __restrict__ WlT, int K, int OUT) {
  int i = blockIdx.x * blockDim.x + threadIdx.x;
  if (i >= K * OUT) return;
  int k = i / OUT, c = i % OUT;
  float f = W[i];
  ushort_t h = f2bf(f);
  ushort_t l = f2bf(f - bf2f(h));
  WhT[(size_t)c * K + k] = h;
  WlT[(size_t)c * K + k] = l;
}

// ---------------------------------------------------------------------------
// bf16-split MFMA GEMM: ht = bf16( (x @ W) * norm_src[:,None] )
// Block: 256 thr = 4 waves (2x2). Wave tile: 32 rows x OUT/2 cols.
// ---------------------------------------------------------------------------
template <int K, int OUT>
__global__ __launch_bounds__(256) void gemm_mfma(const float* __restrict__ x,
                                                 const ushort_t* __restrict__ WhT,
                                                 const ushort_t* __restrict__ WlT,
                                                 const float* __restrict__ norm_src,
                                                 ushort_t* __restrict__ ht, int n) {
  constexpr int BK = 64, KP = BK + 8; // 16B-aligned padded row
  constexpr int NCT = OUT / 32;       // col-tiles per wave (L1: 4, L2: 2)
  __shared__ ushort_t Xh[64][KP], Xl[64][KP];
  __shared__ ushort_t Wh[OUT][KP], Wl[OUT][KP];

  const int tid = threadIdx.x;
  const int wv = tid >> 6;
  const int lane = tid & 63;
  const int wr = wv >> 1; // row half (32 rows)
  const int wc = wv & 1;  // col half (OUT/2 cols)
  const int row0 = blockIdx.x * 64;
  const int fr = lane & 15; // frag row (A) / col (B)
  const int fg = lane >> 4; // k-group

  f32x4 acc[2][NCT];
#pragma unroll
  for (int i = 0; i < 2; ++i)
#pragma unroll
    for (int j = 0; j < NCT; ++j) acc[i][j] = (f32x4){0.f, 0.f, 0.f, 0.f};

#pragma unroll 1
  for (int k0 = 0; k0 < K; k0 += BK) {
    __syncthreads(); // protect LDS from previous iteration's readers
    // stage x chunk (64 rows x 64 k), converting f32 -> bf16 hi/lo
#pragma unroll
    for (int p = 0; p < 4; ++p) {
      int idx = p * 256 + tid;
      int r = idx >> 4, c4 = idx & 15;
      float4 v = *reinterpret_cast<const float4*>(x + (size_t)(row0 + r) * K + k0 + c4 * 4);
      ushort4 h, l;
      h.x = f2bf(v.x); l.x = f2bf(v.x - bf2f(h.x));
      h.y = f2bf(v.y); l.y = f2bf(v.y - bf2f(h.y));
      h.z = f2bf(v.z); l.z = f2bf(v.z - bf2f(h.z));
      h.w = f2bf(v.w); l.w = f2bf(v.w - bf2f(h.w));
      *reinterpret_cast<ushort4*>(&Xh[r][c4 * 4]) = h;
      *reinterpret_cast<ushort4*>(&Xl[r][c4 * 4]) = l;
    }
    // stage W chunk (OUT cols x 64 k, pre-split/transposed in global)
#pragma unroll
    for (int p = 0; p < OUT * 16 / 256; ++p) {
      int idx = p * 256 + tid;
      int c = idx >> 4, k4 = idx & 15;
      *reinterpret_cast<ushort4*>(&Wh[c][k4 * 4]) =
          *reinterpret_cast<const ushort4*>(WhT + (size_t)c * K + k0 + k4 * 4);
      *reinterpret_cast<ushort4*>(&Wl[c][k4 * 4]) =
          *reinterpret_cast<const ushort4*>(WlT + (size_t)c * K + k0 + k4 * 4);
    }
    __syncthreads();

#pragma unroll
    for (int s = 0; s < 2; ++s) { // two 32-k slices
      const int kk = s * 32 + fg * 8;
      bf16x8 ah[2], al[2];
#pragma unroll
      for (int i = 0; i < 2; ++i) {
        int r = wr * 32 + i * 16 + fr;
        ah[i] = *reinterpret_cast<const bf16x8*>(&Xh[r][kk]);
        al[i] = *reinterpret_cast<const bf16x8*>(&Xl[r][kk]);
      }
#pragma unroll
      for (int j = 0; j < NCT; ++j) {
        int c = wc * (OUT / 2) + j * 16 + fr;
        bf16x8 bh = *reinterpret_cast<const bf16x8*>(&Wh[c][kk]);
        bf16x8 bl = *reinterpret_cast<const bf16x8*>(&Wl[c][kk]);
#pragma unroll
        for (int i = 0; i < 2; ++i) {
          acc[i][j] = __builtin_amdgcn_mfma_f32_16x16x32_bf16(ah[i], bh, acc[i][j], 0, 0, 0);
          acc[i][j] = __builtin_amdgcn_mfma_f32_16x16x32_bf16(ah[i], bl, acc[i][j], 0, 0, 0);
          acc[i][j] = __builtin_amdgcn_mfma_f32_16x16x32_bf16(al[i], bh, acc[i][j], 0, 0, 0);
        }
      }
    }
  }

  // epilogue: D col=lane&15, row=(lane>>4)*4+reg (m89); fold norm_src, cast bf16
#pragma unroll
  for (int i = 0; i < 2; ++i) {
#pragma unroll
    for (int q = 0; q < 4; ++q) {
      int row = row0 + wr * 32 + i * 16 + fg * 4 + q;
      float ns = norm_src[row];
#pragma unroll
      for (int j = 0; j < NCT; ++j) {
        int col = wc * (OUT / 2) + j * 16 + fr;
        ht[(size_t)row * OUT + col] = f2bf(acc[i][j][q] * ns);
      }
    }
  }
}

// bf16 gather: 4 bf16 (8B) per lane-group slot
#define GATHB(e, acc)                                                               \
  {                                                                                 \
    float w_ = __int_as_float(e.y);                                                 \
    ushort4 h_ = *reinterpret_cast<const ushort4*>(ht + (size_t)e.x * OUT + cg * 4);\
    acc.x += w_ * bf2f(h_.x);                                                       \
    acc.y += w_ * bf2f(h_.y);                                                       \
    acc.z += w_ * bf2f(h_.z);                                                       \
    acc.w += w_ * bf2f(h_.w);                                                       \
  }

// out[v][col] = tanh( norm_dst[v] * sum_{e in CSR[v]} w_e * ht[src_e][col] + bias[col] )
template <int OUT>
__global__ void aggregate_kernel(const ushort_t* __restrict__ ht, const int* __restrict__ row_ptr,
                                 const int2* __restrict__ csr, const float* __restrict__ norm_dst,
                                 const float* __restrict__ bias, float* __restrict__ out, int n) {
  constexpr int LPN = OUT / 4;
  constexpr int NPB = 256 / LPN;
  const int tid = threadIdx.x;
  const int cg = tid % LPN;
  const int v = blockIdx.x * NPB + tid / LPN;
  if (v >= n) return;

  const int s0 = row_ptr[v];
  const int s1 = row_ptr[v + 1];
  float4 a0 = {0, 0, 0, 0}, a1 = {0, 0, 0, 0}, a2 = {0, 0, 0, 0}, a3 = {0, 0, 0, 0};
  int i = s0;
  for (; i + 4 <= s1; i += 4) {
    int2 e0 = csr[i], e1 = csr[i + 1], e2 = csr[i + 2], e3 = csr[i + 3];
    GATHB(e0, a0);
    GATHB(e1, a1);
    GATHB(e2, a2);
    GATHB(e3, a3);
  }
  for (; i < s1; ++i) {
    int2 e = csr[i];
    GATHB(e, a0);
  }
  float nd = norm_dst[v];
  float4 b4 = *reinterpret_cast<const float4*>(bias + cg * 4);
  float4 r;
  r.x = tanhf((a0.x + a1.x + a2.x + a3.x) * nd + b4.x);
  r.y = tanhf((a0.y + a1.y + a2.y + a3.y) * nd + b4.y);
  r.z = tanhf((a0.z + a1.z + a2.z + a3.z) * nd + b4.z);
  r.w = tanhf((a0.w + a1.w + a2.w + a3.w) * nd + b4.w);
  *reinterpret_cast<float4*>(out + (size_t)v * OUT + cg * 4) = r;
}

// Layer-2 aggregate fused with layer-3 transform.
__global__ void aggregate2_fuse3(const ushort_t* __restrict__ ht, const int* __restrict__ row_ptr,
                                 const int2* __restrict__ csr, const float* __restrict__ norm_dst,
                                 const float* __restrict__ norm_src, const float* __restrict__ bias,
                                 const float* __restrict__ W3, float* __restrict__ ht3, int n) {
  constexpr int OUT = 64;
  constexpr int LPN = OUT / 4; // 16
  constexpr int NPB = 256 / LPN;
  const int tid = threadIdx.x;
  const int cg = tid % LPN;
  const int v = blockIdx.x * NPB + tid / LPN;
  if (v >= n) return;

  const int s0 = row_ptr[v];
  const int s1 = row_ptr[v + 1];
  float4 a0 = {0, 0, 0, 0}, a1 = {0, 0, 0, 0}, a2 = {0, 0, 0, 0}, a3 = {0, 0, 0, 0};
  int i = s0;
  for (; i + 4 <= s1; i += 4) {
    int2 e0 = csr[i], e1 = csr[i + 1], e2 = csr[i + 2], e3 = csr[i + 3];
    GATHB(e0, a0);
    GATHB(e1, a1);
    GATHB(e2, a2);
    GATHB(e3, a3);
  }
  for (; i < s1; ++i) {
    int2 e = csr[i];
    GATHB(e, a0);
  }
  float nd = norm_dst[v];
  float4 b4 = *reinterpret_cast<const float4*>(bias + cg * 4);
  float ox = tanhf((a0.x + a1.x + a2.x + a3.x) * nd + b4.x);
  float oy = tanhf((a0.y + a1.y + a2.y + a3.y) * nd + b4.y);
  float oz = tanhf((a0.z + a1.z + a2.z + a3.z) * nd + b4.z);
  float ow = tanhf((a0.w + a1.w + a2.w + a3.w) * nd + b4.w);
  float4 w3 = *reinterpret_cast<const float4*>(W3 + cg * 4);
  float p = ox * w3.x + oy * w3.y + oz * w3.z + ow * w3.w;
#pragma unroll
  for (int m = 1; m < 16; m <<= 1) p += __shfl_xor(p, m, 64);
  if (cg == 0) ht3[v] = p * norm_src[v];
}

// Layer 3 aggregate: out[v] = norm_dst[v] * sum w_e*ht3[src_e] + b3 (no tanh)
__global__ void aggregate3_kernel(const float* __restrict__ ht3, const int* __restrict__ row_ptr,
                                  const int2* __restrict__ csr, const float* __restrict__ norm_dst,
                                  const float* __restrict__ b3, float* __restrict__ out, int n) {
  int v = blockIdx.x * blockDim.x + threadIdx.x;
  if (v >= n) return;
  const int s0 = row_ptr[v];
  const int s1 = row_ptr[v + 1];
  float p0 = 0.f, p1 = 0.f, p2 = 0.f, p3 = 0.f;
  int i = s0;
  for (; i + 4 <= s1; i += 4) {
    int2 e0 = csr[i], e1 = csr[i + 1], e2 = csr[i + 2], e3 = csr[i + 3];
    p0 += __int_as_float(e0.y) * ht3[e0.x];
    p1 += __int_as_float(e1.y) * ht3[e1.x];
    p2 += __int_as_float(e2.y) * ht3[e2.x];
    p3 += __int_as_float(e3.y) * ht3[e3.x];
  }
  for (; i < s1; ++i) {
    int2 e = csr[i];
    p0 += __int_as_float(e.y) * ht3[e.x];
  }
  out[v] = (p0 + p1 + p2 + p3) * norm_dst[v] + b3[0];
}

extern "C" void kernel_launch(void* const* d_in, const int* in_sizes, int n_in,
                              void* d_out, int out_size, void* d_ws, size_t ws_size,
                              hipStream_t stream) {
  const float* b_z = (const float*)d_in[0];
  const int* src = (const int*)d_in[1];
  const int* dst = (const int*)d_in[2];
  const float* ew = (const float*)d_in[3];
  const float* W1 = (const float*)d_in[4];
  const float* b1 = (const float*)d_in[5];
  const float* W2 = (const float*)d_in[6];
  const float* b2 = (const float*)d_in[7];
  const float* W3 = (const float*)d_in[8];
  const float* b3 = (const float*)d_in[9];

  const int N = in_sizes[0] / 256; // 32768
  const int E = in_sizes[1];       // 524288
  const int N4 = N / 4;
  const int epb = (E + NB - 1) / NB; // 4096

  char* ws = (char*)d_ws;
  size_t off = 0;
  auto alloc = [&](size_t bytes) -> void* {
    void* p = ws + off;
    off += (bytes + 255) & ~(size_t)255;
    return p;
  };

  uint32* part_src = (uint32*)alloc((size_t)NB * N4 * 4); // 4 MB
  uint32* part_dst = (uint32*)alloc((size_t)NB * N4 * 4); // 4 MB
  int* goff = (int*)alloc((size_t)NB * N * 4);            // 16 MB
  float* norm_src = (float*)alloc((size_t)N * 4);
  float* norm_dst = (float*)alloc((size_t)N * 4);
  int* in_deg = (int*)alloc((size_t)N * 4);
  int* row_ptr = (int*)alloc((size_t)(N + 1) * 4);
  int* block_sums = (int*)alloc(256 * 4);
  int* block_offs = (int*)alloc(256 * 4);
  int2* csr = (int2*)alloc((size_t)E * 8);
  ushort_t* HT = (ushort_t*)alloc((size_t)N * 128 * 2); // bf16 ht1 / ht2 (reused)
  float* ACT1 = (float*)alloc((size_t)N * 128 * 4);     // layer1 activation (f32)
  float* HT3 = (float*)alloc((size_t)N * 4);
  ushort_t* WhT1 = (ushort_t*)alloc((size_t)256 * 128 * 2);
  ushort_t* WlT1 = (ushort_t*)alloc((size_t)256 * 128 * 2);
  ushort_t* WhT2 = (ushort_t*)alloc((size_t)128 * 64 * 2);
  ushort_t* WlT2 = (ushort_t*)alloc((size_t)128 * 64 * 2);

  const int nBlocks = (N + 255) / 256; // 128

  lds_hist_kernel<<<NB, 1024, 0, stream>>>(src, dst, part_src, part_dst, E, epb);
  reduce_norm_kernel<<<(N4 + 255) / 256, 256, 0, stream>>>(part_src, part_dst, norm_src,
                                                           norm_dst, in_deg, N4);
  scan_partials_a<<<nBlocks, 256, 0, stream>>>(in_deg, block_sums, N);
  scan_partials_b<<<1, 256, 0, stream>>>(block_sums, block_offs, nBlocks);
  scan_write<<<nBlocks, 256, 0, stream>>>(in_deg, block_offs, row_ptr, N);
  group_offs_kernel<<<nBlocks, 256, 0, stream>>>(part_dst, row_ptr, goff, N);
  scatter_kernel<<<NB, 1024, 0, stream>>>(src, dst, ew, goff, csr, N, E, epb);
  wsplit_kernel<<<(256 * 128 + 255) / 256, 256, 0, stream>>>(W1, WhT1, WlT1, 256, 128);
  wsplit_kernel<<<(128 * 64 + 255) / 256, 256, 0, stream>>>(W2, WhT2, WlT2, 128, 64);

  // Layer 1: 256 -> 128, tanh
  gemm_mfma<256, 128><<<N / 64, 256, 0, stream>>>(b_z, WhT1, WlT1, norm_src, HT, N);
  aggregate_kernel<128><<<(N + 7) / 8, 256, 0, stream>>>(HT, row_ptr, csr, norm_dst, b1, ACT1, N);
  // Layer 2: 128 -> 64 (tanh) fused with layer-3 transform (64 -> 1)
  gemm_mfma<128, 64><<<N / 64, 256, 0, stream>>>(ACT1, WhT2, WlT2, norm_src, HT, N);
  aggregate2_fuse3<<<(N + 15) / 16, 256, 0, stream>>>(HT, row_ptr, csr, norm_dst, norm_src, b2,
                                                      W3, HT3, N);
  // Layer 3 aggregate: 1 col, no tanh
  aggregate3_kernel<<<nBlocks, 256, 0, stream>>>(HT3, row_ptr, csr, norm_dst, b3,
                                                 (float*)d_out, N);
}

// Round 12
// 111.486 us; speedup vs baseline: 1.5086x; 1.1118x over previous
//
#include <hip/hip_runtime.h>

// ---------------------------------------------------------------------------
// GCN 3-layer forward on a static graph.
// R2-R6: tiled SGEMM, parallel scan, int2 CSR, LDS histograms/rank-scatter.
// R7-R9: f32 SGEMM structurally capped ~45us (LDS pipe vs 4 SIMDs).
// R10: bf16 split-precision MFMA GEMM (hh+hl+lh, f32 acc): 168->141.5us.
// R11: bf16 HT gather operand: 141.5->124us, absmax 6.1e-5 (5.7x margin).
// R12: preprocessing occupancy+traffic. NB 128->256 (hist/scatter 1 block/CU,
//     was half the chip idle); goff int32 16MB -> gpre u8 8MB (+row_ptr read,
//     L2-resident); group_offs fused into scan_write; reduce_norm 2-stage
//     (512-block r-segment partials, was 32 blocks = 7/8 CUs idle); wsplits
//     fused. 14 -> 12 launches.
// ---------------------------------------------------------------------------

#define NB 256     // edge groups == hist/scatter blocks
#define NW4 8192   // N/4 packed words (N = 32768)
#define RSEG 8     // r-segments for the 2-stage partials reduction

typedef unsigned int uint32;
typedef unsigned char uchar_t;
typedef unsigned short ushort_t;
typedef __attribute__((ext_vector_type(8))) short bf16x8;
typedef __attribute__((ext_vector_type(4))) float f32x4;

__device__ inline ushort_t f2bf(float f) {
  uint32 u = __float_as_uint(f);
  u += 0x7fffu + ((u >> 16) & 1u);
  return (ushort_t)(u >> 16);
}
__device__ inline float bf2f(ushort_t h) { return __uint_as_float(((uint32)h) << 16); }

// --- per-block src+dst histograms, packed u8 x4 per word --------------------
// part layout: part[a][r][w], a in {src=0, dst=1}.
__global__ __launch_bounds__(1024) void lds_hist_kernel(const int* __restrict__ src,
                                                        const int* __restrict__ dst,
                                                        uint32* __restrict__ part,
                                                        int e, int epb) {
  __shared__ uint32 hs[NW4];
  __shared__ uint32 hd[NW4];
  const int t = threadIdx.x;
  for (int w = t; w < NW4; w += 1024) {
    hs[w] = 0;
    hd[w] = 0;
  }
  __syncthreads();
  const int base = blockIdx.x * epb;
  for (int k = t; k < epb; k += 1024) {
    int i = base + k;
    if (i < e) {
      int s = src[i], d = dst[i];
      atomicAdd(&hs[s >> 2], 1u << ((s & 3) * 8));
      atomicAdd(&hd[d >> 2], 1u << ((d & 3) * 8));
    }
  }
  __syncthreads();
  uint32* ps = part + (size_t)blockIdx.x * NW4;
  uint32* pd = part + (size_t)(NB + blockIdx.x) * NW4;
  for (int w = t; w < NW4; w += 1024) {
    ps[w] = hs[w];
    pd[w] = hd[w];
  }
}

// --- stage A: sum NB/RSEG r-values per word per segment ---------------------
// psum[a][seg][w]; grid (n4/256, RSEG, 2).
__global__ __launch_bounds__(256) void norm_partial(const uint32* __restrict__ part,
                                                    uint32* __restrict__ psum, int n4) {
  const int w = blockIdx.x * 256 + threadIdx.x;
  const int seg = blockIdx.y;
  const int a = blockIdx.z;
  const uint32* p = part + (size_t)a * NB * n4 + (size_t)seg * (NB / RSEG) * n4 + w;
  uint32 s = 0;
#pragma unroll
  for (int r = 0; r < NB / RSEG; ++r) s += p[(size_t)r * n4];
  psum[(size_t)a * RSEG * n4 + (size_t)seg * n4 + w] = s;
}

// --- stage B: fold segments, unpack -> norms/in_deg, chunk sums (scan A) ----
__global__ __launch_bounds__(256) void norm_final(const uint32* __restrict__ psum,
                                                  float* __restrict__ norm_src,
                                                  float* __restrict__ norm_dst,
                                                  int* __restrict__ in_deg,
                                                  int* __restrict__ block_sums, int n4) {
  const int w = blockIdx.x * 256 + threadIdx.x;
  if (w >= n4) return;
  uint32 ss = 0, sd = 0;
#pragma unroll
  for (int seg = 0; seg < RSEG; ++seg) {
    ss += psum[(size_t)seg * n4 + w];
    sd += psum[(size_t)(RSEG + seg) * n4 + w];
  }
  int idsum = 0;
#pragma unroll
  for (int j = 0; j < 4; ++j) {
    int v = w * 4 + j;
    int od = (ss >> (j * 8)) & 0xff;
    int id = (sd >> (j * 8)) & 0xff;
    norm_src[v] = 1.0f / sqrtf((float)max(od, 1));
    norm_dst[v] = 1.0f / sqrtf((float)max(id, 1));
    in_deg[v] = id;
    idsum += id;
  }
  // chunk (256 nodes == 64 words == one wave) sum for the scan
#pragma unroll
  for (int off = 32; off > 0; off >>= 1) idsum += __shfl_down(idsum, off, 64);
  if ((threadIdx.x & 63) == 0) block_sums[w >> 6] = idsum;
}

__global__ __launch_bounds__(256) void scan_partials_b(int* __restrict__ block_sums,
                                                       int* __restrict__ block_offs, int nb) {
  __shared__ int sh[256];
  const int t = threadIdx.x;
  sh[t] = (t < nb) ? block_sums[t] : 0;
  __syncthreads();
  for (int off = 1; off < 256; off <<= 1) {
    int v = sh[t];
    int add = (t >= off) ? sh[t - off] : 0;
    __syncthreads();
    sh[t] = v + add;
    __syncthreads();
  }
  if (t < nb) block_offs[t] = (t > 0) ? sh[t - 1] : 0; // exclusive
}

// --- per-chunk scan -> row_ptr, then per-(group,node) u8 offsets ------------
__global__ __launch_bounds__(256) void scan_write_goffs(const int* __restrict__ in_deg,
                                                        const int* __restrict__ block_offs,
                                                        const uint32* __restrict__ part_dst,
                                                        int* __restrict__ row_ptr,
                                                        uchar_t* __restrict__ gpre, int n) {
  __shared__ int sh[256];
  const int t = threadIdx.x;
  const int gid = blockIdx.x * 256 + t;
  int d = (gid < n) ? in_deg[gid] : 0;
  sh[t] = d;
  __syncthreads();
  for (int off = 1; off < 256; off <<= 1) {
    int v = sh[t];
    int add = (t >= off) ? sh[t - off] : 0;
    __syncthreads();
    sh[t] = v + add;
    __syncthreads();
  }
  if (gid >= n) return;
  int excl = block_offs[blockIdx.x] + sh[t] - d;
  row_ptr[gid] = excl;
  if (gid == n - 1) row_ptr[n] = excl + d;
  const int w = gid >> 2;
  const int shft = (gid & 3) * 8;
  const int n4 = n >> 2;
  int cum = 0;
#pragma unroll 8
  for (int r = 0; r < NB; ++r) {
    gpre[(size_t)r * n + gid] = (uchar_t)cum;
    cum += (part_dst[(size_t)r * n4 + w] >> shft) & 0xff;
  }
}

// --- scatter: LDS rank + row_ptr[d] + gpre[r][d], no global atomics ---------
__global__ __launch_bounds__(1024) void scatter_kernel(const int* __restrict__ src,
                                                       const int* __restrict__ dst,
                                                       const float* __restrict__ ew,
                                                       const int* __restrict__ row_ptr,
                                                       const uchar_t* __restrict__ gpre,
                                                       int2* __restrict__ csr,
                                                       int n, int e, int epb) {
  __shared__ uint32 rk[NW4];
  const int t = threadIdx.x;
  for (int w = t; w < NW4; w += 1024) rk[w] = 0;
  __syncthreads();
  const int base = blockIdx.x * epb;
  const uchar_t* gp = gpre + (size_t)blockIdx.x * n;
  for (int k = t; k < epb; k += 1024) {
    int i = base + k;
    if (i < e) {
      int d = dst[i];
      uint32 sh = (d & 3) * 8;
      uint32 old = atomicAdd(&rk[d >> 2], 1u << sh);
      int rank = (old >> sh) & 0xff;
      int pos = row_ptr[d] + (int)gp[d] + rank;
      csr[pos] = make_int2(src[i], __float_as_int(ew[i]));
    }
  }
}

// --- W pre-split for both layers in one launch ------------------------------
__global__ void wsplit_all(const float* __restrict__ W1, const float* __restrict__ W2,
                           ushort_t* __restrict__ WhT1, ushort_t* __restrict__ WlT1,
                           ushort_t* __restrict__ WhT2, ushort_t* __restrict__ WlT2) {
  int i = blockIdx.x * blockDim.x + threadIdx.x;
  if (i < 256 * 128) {
    int k = i / 128, c = i % 128;
    float f = W1[i];
    ushort_t h = f2bf(f);
    WhT1[(size_t)c * 256 + k] = h;
    WlT1[(size_t)c * 256 + k] = f2bf(f - bf2f(h));
  } else if (i < 256 * 128 + 128 * 64) {
    int j = i - 256 * 128;
    int k = j / 64, c = j % 64;
    float f = W2[j];
    ushort_t h = f2bf(f);
    WhT2[(size_t)c * 128 + k] = h;
    WlT2[(size_t)c * 128 + k] = f2bf(f - bf2f(h));
  }
}

// ---------------------------------------------------------------------------
// bf16-split MFMA GEMM: ht = bf16( (x @ W) * norm_src[:,None] )
// ---------------------------------------------------------------------------
template <int K, int OUT>
__global__ __launch_bounds__(256) void gemm_mfma(const float* __restrict__ x,
                                                 const ushort_t* __restrict__ WhT,
                                                 const ushort_t* __restrict__ WlT,
                                                 const float* __restrict__ norm_src,
                                                 ushort_t* __restrict__ ht, int n) {
  constexpr int BK = 64, KP = BK + 8;
  constexpr int NCT = OUT / 32;
  __shared__ ushort_t Xh[64][KP], Xl[64][KP];
  __shared__ ushort_t Wh[OUT][KP], Wl[OUT][KP];

  const int tid = threadIdx.x;
  const int wv = tid >> 6;
  const int lane = tid & 63;
  const int wr = wv >> 1;
  const int wc = wv & 1;
  const int row0 = blockIdx.x * 64;
  const int fr = lane & 15;
  const int fg = lane >> 4;

  f32x4 acc[2][NCT];
#pragma unroll
  for (int i = 0; i < 2; ++i)
#pragma unroll
    for (int j = 0; j < NCT; ++j) acc[i][j] = (f32x4){0.f, 0.f, 0.f, 0.f};

#pragma unroll 1
  for (int k0 = 0; k0 < K; k0 += BK) {
    __syncthreads();
#pragma unroll
    for (int p = 0; p < 4; ++p) {
      int idx = p * 256 + tid;
      int r = idx >> 4, c4 = idx & 15;
      float4 v = *reinterpret_cast<const float4*>(x + (size_t)(row0 + r) * K + k0 + c4 * 4);
      ushort4 h, l;
      h.x = f2bf(v.x); l.x = f2bf(v.x - bf2f(h.x));
      h.y = f2bf(v.y); l.y = f2bf(v.y - bf2f(h.y));
      h.z = f2bf(v.z); l.z = f2bf(v.z - bf2f(h.z));
      h.w = f2bf(v.w); l.w = f2bf(v.w - bf2f(h.w));
      *reinterpret_cast<ushort4*>(&Xh[r][c4 * 4]) = h;
      *reinterpret_cast<ushort4*>(&Xl[r][c4 * 4]) = l;
    }
#pragma unroll
    for (int p = 0; p < OUT * 16 / 256; ++p) {
      int idx = p * 256 + tid;
      int c = idx >> 4, k4 = idx & 15;
      *reinterpret_cast<ushort4*>(&Wh[c][k4 * 4]) =
          *reinterpret_cast<const ushort4*>(WhT + (size_t)c * K + k0 + k4 * 4);
      *reinterpret_cast<ushort4*>(&Wl[c][k4 * 4]) =
          *reinterpret_cast<const ushort4*>(WlT + (size_t)c * K + k0 + k4 * 4);
    }
    __syncthreads();

#pragma unroll
    for (int s = 0; s < 2; ++s) {
      const int kk = s * 32 + fg * 8;
      bf16x8 ah[2], al[2];
#pragma unroll
      for (int i = 0; i < 2; ++i) {
        int r = wr * 32 + i * 16 + fr;
        ah[i] = *reinterpret_cast<const bf16x8*>(&Xh[r][kk]);
        al[i] = *reinterpret_cast<const bf16x8*>(&Xl[r][kk]);
      }
#pragma unroll
      for (int j = 0; j < NCT; ++j) {
        int c = wc * (OUT / 2) + j * 16 + fr;
        bf16x8 bh = *reinterpret_cast<const bf16x8*>(&Wh[c][kk]);
        bf16x8 bl = *reinterpret_cast<const bf16x8*>(&Wl[c][kk]);
#pragma unroll
        for (int i = 0; i < 2; ++i) {
          acc[i][j] = __builtin_amdgcn_mfma_f32_16x16x32_bf16(ah[i], bh, acc[i][j], 0, 0, 0);
          acc[i][j] = __builtin_amdgcn_mfma_f32_16x16x32_bf16(ah[i], bl, acc[i][j], 0, 0, 0);
          acc[i][j] = __builtin_amdgcn_mfma_f32_16x16x32_bf16(al[i], bh, acc[i][j], 0, 0, 0);
        }
      }
    }
  }

#pragma unroll
  for (int i = 0; i < 2; ++i) {
#pragma unroll
    for (int q = 0; q < 4; ++q) {
      int row = row0 + wr * 32 + i * 16 + fg * 4 + q;
      float ns = norm_src[row];
#pragma unroll
      for (int j = 0; j < NCT; ++j) {
        int col = wc * (OUT / 2) + j * 16 + fr;
        ht[(size_t)row * OUT + col] = f2bf(acc[i][j][q] * ns);
      }
    }
  }
}

// bf16 gather: 4 bf16 (8B) per lane-group slot
#define GATHB(e, acc)                                                               \
  {                                                                                 \
    float w_ = __int_as_float(e.y);                                                 \
    ushort4 h_ = *reinterpret_cast<const ushort4*>(ht + (size_t)e.x * OUT + cg * 4);\
    acc.x += w_ * bf2f(h_.x);                                                       \
    acc.y += w_ * bf2f(h_.y);                                                       \
    acc.z += w_ * bf2f(h_.z);                                                       \
    acc.w += w_ * bf2f(h_.w);                                                       \
  }

template <int OUT>
__global__ void aggregate_kernel(const ushort_t* __restrict__ ht, const int* __restrict__ row_ptr,
                                 const int2* __restrict__ csr, const float* __restrict__ norm_dst,
                                 const float* __restrict__ bias, float* __restrict__ out, int n) {
  constexpr int LPN = OUT / 4;
  constexpr int NPB = 256 / LPN;
  const int tid = threadIdx.x;
  const int cg = tid % LPN;
  const int v = blockIdx.x * NPB + tid / LPN;
  if (v >= n) return;

  const int s0 = row_ptr[v];
  const int s1 = row_ptr[v + 1];
  float4 a0 = {0, 0, 0, 0}, a1 = {0, 0, 0, 0}, a2 = {0, 0, 0, 0}, a3 = {0, 0, 0, 0};
  int i = s0;
  for (; i + 4 <= s1; i += 4) {
    int2 e0 = csr[i], e1 = csr[i + 1], e2 = csr[i + 2], e3 = csr[i + 3];
    GATHB(e0, a0);
    GATHB(e1, a1);
    GATHB(e2, a2);
    GATHB(e3, a3);
  }
  for (; i < s1; ++i) {
    int2 e = csr[i];
    GATHB(e, a0);
  }
  float nd = norm_dst[v];
  float4 b4 = *reinterpret_cast<const float4*>(bias + cg * 4);
  float4 r;
  r.x = tanhf((a0.x + a1.x + a2.x + a3.x) * nd + b4.x);
  r.y = tanhf((a0.y + a1.y + a2.y + a3.y) * nd + b4.y);
  r.z = tanhf((a0.z + a1.z + a2.z + a3.z) * nd + b4.z);
  r.w = tanhf((a0.w + a1.w + a2.w + a3.w) * nd + b4.w);
  *reinterpret_cast<float4*>(out + (size_t)v * OUT + cg * 4) = r;
}

__global__ void aggregate2_fuse3(const ushort_t* __restrict__ ht, const int* __restrict__ row_ptr,
                                 const int2* __restrict__ csr, const float* __restrict__ norm_dst,
                                 const float* __restrict__ norm_src, const float* __restrict__ bias,
                                 const float* __restrict__ W3, float* __restrict__ ht3, int n) {
  constexpr int OUT = 64;
  constexpr int LPN = OUT / 4; // 16
  constexpr int NPB = 256 / LPN;
  const int tid = threadIdx.x;
  const int cg = tid % LPN;
  const int v = blockIdx.x * NPB + tid / LPN;
  if (v >= n) return;

  const int s0 = row_ptr[v];
  const int s1 = row_ptr[v + 1];
  float4 a0 = {0, 0, 0, 0}, a1 = {0, 0, 0, 0}, a2 = {0, 0, 0, 0}, a3 = {0, 0, 0, 0};
  int i = s0;
  for (; i + 4 <= s1; i += 4) {
    int2 e0 = csr[i], e1 = csr[i + 1], e2 = csr[i + 2], e3 = csr[i + 3];
    GATHB(e0, a0);
    GATHB(e1, a1);
    GATHB(e2, a2);
    GATHB(e3, a3);
  }
  for (; i < s1; ++i) {
    int2 e = csr[i];
    GATHB(e, a0);
  }
  float nd = norm_dst[v];
  float4 b4 = *reinterpret_cast<const float4*>(bias + cg * 4);
  float ox = tanhf((a0.x + a1.x + a2.x + a3.x) * nd + b4.x);
  float oy = tanhf((a0.y + a1.y + a2.y + a3.y) * nd + b4.y);
  float oz = tanhf((a0.z + a1.z + a2.z + a3.z) * nd + b4.z);
  float ow = tanhf((a0.w + a1.w + a2.w + a3.w) * nd + b4.w);
  float4 w3 = *reinterpret_cast<const float4*>(W3 + cg * 4);
  float p = ox * w3.x + oy * w3.y + oz * w3.z + ow * w3.w;
#pragma unroll
  for (int m = 1; m < 16; m <<= 1) p += __shfl_xor(p, m, 64);
  if (cg == 0) ht3[v] = p * norm_src[v];
}

__global__ void aggregate3_kernel(const float* __restrict__ ht3, const int* __restrict__ row_ptr,
                                  const int2* __restrict__ csr, const float* __restrict__ norm_dst,
                                  const float* __restrict__ b3, float* __restrict__ out, int n) {
  int v = blockIdx.x * blockDim.x + threadIdx.x;
  if (v >= n) return;
  const int s0 = row_ptr[v];
  const int s1 = row_ptr[v + 1];
  float p0 = 0.f, p1 = 0.f, p2 = 0.f, p3 = 0.f;
  int i = s0;
  for (; i + 4 <= s1; i += 4) {
    int2 e0 = csr[i], e1 = csr[i + 1], e2 = csr[i + 2], e3 = csr[i + 3];
    p0 += __int_as_float(e0.y) * ht3[e0.x];
    p1 += __int_as_float(e1.y) * ht3[e1.x];
    p2 += __int_as_float(e2.y) * ht3[e2.x];
    p3 += __int_as_float(e3.y) * ht3[e3.x];
  }
  for (; i < s1; ++i) {
    int2 e = csr[i];
    p0 += __int_as_float(e.y) * ht3[e.x];
  }
  out[v] = (p0 + p1 + p2 + p3) * norm_dst[v] + b3[0];
}

extern "C" void kernel_launch(void* const* d_in, const int* in_sizes, int n_in,
                              void* d_out, int out_size, void* d_ws, size_t ws_size,
                              hipStream_t stream) {
  const float* b_z = (const float*)d_in[0];
  const int* src = (const int*)d_in[1];
  const int* dst = (const int*)d_in[2];
  const float* ew = (const float*)d_in[3];
  const float* W1 = (const float*)d_in[4];
  const float* b1 = (const float*)d_in[5];
  const float* W2 = (const float*)d_in[6];
  const float* b2 = (const float*)d_in[7];
  const float* W3 = (const float*)d_in[8];
  const float* b3 = (const float*)d_in[9];

  const int N = in_sizes[0] / 256; // 32768
  const int E = in_sizes[1];       // 524288
  const int N4 = N / 4;            // 8192
  const int epb = (E + NB - 1) / NB; // 2048

  char* ws = (char*)d_ws;
  size_t off = 0;
  auto alloc = [&](size_t bytes) -> void* {
    void* p = ws + off;
    off += (bytes + 255) & ~(size_t)255;
    return p;
  };

  uint32* part = (uint32*)alloc((size_t)2 * NB * N4 * 4);      // 16 MB: [src|dst][r][w]
  uint32* psum = (uint32*)alloc((size_t)2 * RSEG * N4 * 4);    // 512 KB
  uchar_t* gpre = (uchar_t*)alloc((size_t)NB * N);             // 8 MB
  float* norm_src = (float*)alloc((size_t)N * 4);
  float* norm_dst = (float*)alloc((size_t)N * 4);
  int* in_deg = (int*)alloc((size_t)N * 4);
  int* row_ptr = (int*)alloc((size_t)(N + 1) * 4);
  int* block_sums = (int*)alloc(256 * 4);
  int* block_offs = (int*)alloc(256 * 4);
  int2* csr = (int2*)alloc((size_t)E * 8);
  ushort_t* HT = (ushort_t*)alloc((size_t)N * 128 * 2); // bf16 ht1 / ht2 (reused)
  float* ACT1 = (float*)alloc((size_t)N * 128 * 4);     // layer1 activation (f32)
  float* HT3 = (float*)alloc((size_t)N * 4);
  ushort_t* WhT1 = (ushort_t*)alloc((size_t)256 * 128 * 2);
  ushort_t* WlT1 = (ushort_t*)alloc((size_t)256 * 128 * 2);
  ushort_t* WhT2 = (ushort_t*)alloc((size_t)128 * 64 * 2);
  ushort_t* WlT2 = (ushort_t*)alloc((size_t)128 * 64 * 2);

  const uint32* part_dst = part + (size_t)NB * N4;
  const int nBlocks = (N + 255) / 256; // 128

  lds_hist_kernel<<<NB, 1024, 0, stream>>>(src, dst, part, E, epb);
  norm_partial<<<dim3(N4 / 256, RSEG, 2), 256, 0, stream>>>(part, psum, N4);
  norm_final<<<N4 / 256, 256, 0, stream>>>(psum, norm_src, norm_dst, in_deg, block_sums, N4);
  scan_partials_b<<<1, 256, 0, stream>>>(block_sums, block_offs, nBlocks);
  scan_write_goffs<<<nBlocks, 256, 0, stream>>>(in_deg, block_offs, part_dst, row_ptr, gpre, N);
  scatter_kernel<<<NB, 1024, 0, stream>>>(src, dst, ew, row_ptr, gpre, csr, N, E, epb);
  wsplit_all<<<(256 * 128 + 128 * 64 + 255) / 256, 256, 0, stream>>>(W1, W2, WhT1, WlT1,
                                                                     WhT2, WlT2);

  // Layer 1: 256 -> 128, tanh
  gemm_mfma<256, 128><<<N / 64, 256, 0, stream>>>(b_z, WhT1, WlT1, norm_src, HT, N);
  aggregate_kernel<128><<<(N + 7) / 8, 256, 0, stream>>>(HT, row_ptr, csr, norm_dst, b1, ACT1, N);
  // Layer 2: 128 -> 64 (tanh) fused with layer-3 transform (64 -> 1)
  gemm_mfma<128, 64><<<N / 64, 256, 0, stream>>>(ACT1, WhT2, WlT2, norm_src, HT, N);
  aggregate2_fuse3<<<(N + 15) / 16, 256, 0, stream>>>(HT, row_ptr, csr, norm_dst, norm_src, b2,
                                                      W3, HT3, N);
  // Layer 3 aggregate: 1 col, no tanh
  aggregate3_kernel<<<nBlocks, 256, 0, stream>>>(HT3, row_ptr, csr, norm_dst, b3,
                                                 (float*)d_out, N);
}

// Round 13
// 107.724 us; speedup vs baseline: 1.5613x; 1.0349x over previous
//
#include <hip/hip_runtime.h>

// ---------------------------------------------------------------------------
// GCN 3-layer forward on a static graph.
// R2-R6: tiled SGEMM, parallel scan, int2 CSR, LDS histograms/rank-scatter.
// R7-R9: f32 SGEMM structurally capped ~45us (LDS pipe vs 4 SIMDs).
// R10: bf16 split-precision MFMA GEMM (hh+hl+lh, f32 acc): 168->141.5us.
// R11: bf16 HT gather operand: 141.5->124us (absmax 3e-5 -> 6.1e-5).
// R12: preprocessing occupancy (NB=256, u8 gpre, 2-stage norm reduce): ->111.5us.
// R13: (a) gemm register-prefetch of next x/W chunk (cold-load latency was
//     exposed between barriers at 2 waves/SIMD); (b) ACT1 bf16 h-only (R11
//     anchor: +~3e-5 absmax) -> gemm2 reads bf16 direct, 2 MFMAs, no convert;
//     (c) norm_src folded into csr weight at scatter (commutes with @W);
//     (d) wsplit folded into hist grid, scan_b inlined into scan_write.
//     12 -> 10 launches.
// ---------------------------------------------------------------------------

#define NB 256     // edge groups == hist/scatter blocks
#define NW4 8192   // N/4 packed words (N = 32768)
#define RSEG 8     // r-segments for the 2-stage partials reduction

typedef unsigned int uint32;
typedef unsigned char uchar_t;
typedef unsigned short ushort_t;
typedef __attribute__((ext_vector_type(8))) short bf16x8;
typedef __attribute__((ext_vector_type(4))) float f32x4;

__device__ inline ushort_t f2bf(float f) {
  uint32 u = __float_as_uint(f);
  u += 0x7fffu + ((u >> 16) & 1u);
  return (ushort_t)(u >> 16);
}
__device__ inline float bf2f(ushort_t h) { return __uint_as_float(((uint32)h) << 16); }

// --- hist (blocks < NB) + W pre-split (blocks >= NB) ------------------------
// part layout: part[a][r][w], a in {src=0, dst=1}.
__global__ __launch_bounds__(1024) void hist_wsplit_kernel(
    const int* __restrict__ src, const int* __restrict__ dst, uint32* __restrict__ part,
    const float* __restrict__ W1, const float* __restrict__ W2,
    ushort_t* __restrict__ WhT1, ushort_t* __restrict__ WlT1,
    ushort_t* __restrict__ WhT2, ushort_t* __restrict__ WlT2, int e, int epb) {
  const int t = threadIdx.x;
  if (blockIdx.x >= NB) {
    int i = (blockIdx.x - NB) * 1024 + t;
    if (i < 256 * 128) {
      int k = i / 128, c = i % 128;
      float f = W1[i];
      ushort_t h = f2bf(f);
      WhT1[(size_t)c * 256 + k] = h;
      WlT1[(size_t)c * 256 + k] = f2bf(f - bf2f(h));
    } else if (i < 256 * 128 + 128 * 64) {
      int j = i - 256 * 128;
      int k = j / 64, c = j % 64;
      float f = W2[j];
      ushort_t h = f2bf(f);
      WhT2[(size_t)c * 128 + k] = h;
      WlT2[(size_t)c * 128 + k] = f2bf(f - bf2f(h));
    }
    return;
  }
  __shared__ uint32 hs[NW4];
  __shared__ uint32 hd[NW4];
  for (int w = t; w < NW4; w += 1024) {
    hs[w] = 0;
    hd[w] = 0;
  }
  __syncthreads();
  const int base = blockIdx.x * epb;
  for (int k = t; k < epb; k += 1024) {
    int i = base + k;
    if (i < e) {
      int s = src[i], d = dst[i];
      atomicAdd(&hs[s >> 2], 1u << ((s & 3) * 8));
      atomicAdd(&hd[d >> 2], 1u << ((d & 3) * 8));
    }
  }
  __syncthreads();
  uint32* ps = part + (size_t)blockIdx.x * NW4;
  uint32* pd = part + (size_t)(NB + blockIdx.x) * NW4;
  for (int w = t; w < NW4; w += 1024) {
    ps[w] = hs[w];
    pd[w] = hd[w];
  }
}

// --- stage A: sum NB/RSEG r-values per word per segment ---------------------
__global__ __launch_bounds__(256) void norm_partial(const uint32* __restrict__ part,
                                                    uint32* __restrict__ psum, int n4) {
  const int w = blockIdx.x * 256 + threadIdx.x;
  const int seg = blockIdx.y;
  const int a = blockIdx.z;
  const uint32* p = part + (size_t)a * NB * n4 + (size_t)seg * (NB / RSEG) * n4 + w;
  uint32 s = 0;
#pragma unroll
  for (int r = 0; r < NB / RSEG; ++r) s += p[(size_t)r * n4];
  psum[(size_t)a * RSEG * n4 + (size_t)seg * n4 + w] = s;
}

// --- stage B: fold segments -> norms/in_deg + chunk sums --------------------
__global__ __launch_bounds__(256) void norm_final(const uint32* __restrict__ psum,
                                                  float* __restrict__ norm_src,
                                                  float* __restrict__ norm_dst,
                                                  int* __restrict__ in_deg,
                                                  int* __restrict__ block_sums, int n4) {
  const int w = blockIdx.x * 256 + threadIdx.x;
  if (w >= n4) return;
  uint32 ss = 0, sd = 0;
#pragma unroll
  for (int seg = 0; seg < RSEG; ++seg) {
    ss += psum[(size_t)seg * n4 + w];
    sd += psum[(size_t)(RSEG + seg) * n4 + w];
  }
  int idsum = 0;
#pragma unroll
  for (int j = 0; j < 4; ++j) {
    int v = w * 4 + j;
    int od = (ss >> (j * 8)) & 0xff;
    int id = (sd >> (j * 8)) & 0xff;
    norm_src[v] = 1.0f / sqrtf((float)max(od, 1));
    norm_dst[v] = 1.0f / sqrtf((float)max(id, 1));
    in_deg[v] = id;
    idsum += id;
  }
#pragma unroll
  for (int off = 32; off > 0; off >>= 1) idsum += __shfl_down(idsum, off, 64);
  if ((threadIdx.x & 63) == 0) block_sums[w >> 6] = idsum;
}

// --- chunk scan (block offset inlined) -> row_ptr + u8 group offsets --------
__global__ __launch_bounds__(256) void scan_write_goffs(const int* __restrict__ in_deg,
                                                        const int* __restrict__ block_sums,
                                                        const uint32* __restrict__ part_dst,
                                                        int* __restrict__ row_ptr,
                                                        uchar_t* __restrict__ gpre, int n) {
  __shared__ int sh[256];
  __shared__ int s_boff;
  const int t = threadIdx.x;
  const int gid = blockIdx.x * 256 + t;
  // inline exclusive block offset: sum of block_sums[0..blockIdx.x)
  {
    int v = (t < blockIdx.x && t < 128) ? block_sums[t] : 0;
#pragma unroll
    for (int off = 32; off > 0; off >>= 1) v += __shfl_down(v, off, 64);
    if ((t & 63) == 0) sh[t >> 6] = v;
    __syncthreads();
    if (t == 0) s_boff = sh[0] + sh[1] + sh[2] + sh[3];
    __syncthreads();
  }
  int d = (gid < n) ? in_deg[gid] : 0;
  sh[t] = d;
  __syncthreads();
  for (int off = 1; off < 256; off <<= 1) {
    int v = sh[t];
    int add = (t >= off) ? sh[t - off] : 0;
    __syncthreads();
    sh[t] = v + add;
    __syncthreads();
  }
  if (gid >= n) return;
  int excl = s_boff + sh[t] - d;
  row_ptr[gid] = excl;
  if (gid == n - 1) row_ptr[n] = excl + d;
  const int w = gid >> 2;
  const int shft = (gid & 3) * 8;
  const int n4 = n >> 2;
  int cum = 0;
#pragma unroll 8
  for (int r = 0; r < NB; ++r) {
    gpre[(size_t)r * n + gid] = (uchar_t)cum;
    cum += (part_dst[(size_t)r * n4 + w] >> shft) & 0xff;
  }
}

// --- scatter: LDS rank + row_ptr + gpre; csr weight = ew * norm_src[src] ----
__global__ __launch_bounds__(1024) void scatter_kernel(const int* __restrict__ src,
                                                       const int* __restrict__ dst,
                                                       const float* __restrict__ ew,
                                                       const float* __restrict__ norm_src,
                                                       const int* __restrict__ row_ptr,
                                                       const uchar_t* __restrict__ gpre,
                                                       int2* __restrict__ csr,
                                                       int n, int e, int epb) {
  __shared__ uint32 rk[NW4];
  const int t = threadIdx.x;
  for (int w = t; w < NW4; w += 1024) rk[w] = 0;
  __syncthreads();
  const int base = blockIdx.x * epb;
  const uchar_t* gp = gpre + (size_t)blockIdx.x * n;
  for (int k = t; k < epb; k += 1024) {
    int i = base + k;
    if (i < e) {
      int s = src[i];
      int d = dst[i];
      uint32 sh = (d & 3) * 8;
      uint32 old = atomicAdd(&rk[d >> 2], 1u << sh);
      int rank = (old >> sh) & 0xff;
      int pos = row_ptr[d] + (int)gp[d] + rank;
      csr[pos] = make_int2(s, __float_as_int(ew[i] * norm_src[s]));
    }
  }
}

// ---------------------------------------------------------------------------
// bf16-split MFMA GEMM (f32 input): ht = bf16(x @ W); norm folded into csr_w.
// Register-prefetch of next chunk's x and W hides cold-load latency under MFMA.
// ---------------------------------------------------------------------------
template <int K, int OUT>
__global__ __launch_bounds__(256) void gemm_mfma(const float* __restrict__ x,
                                                 const ushort_t* __restrict__ WhT,
                                                 const ushort_t* __restrict__ WlT,
                                                 ushort_t* __restrict__ ht, int n) {
  constexpr int BK = 64, KP = BK + 8;
  constexpr int NCT = OUT / 32;
  constexpr int NWLD = OUT * 16 / 256; // W ushort4 loads per thread per chunk
  __shared__ ushort_t Xh[64][KP], Xl[64][KP];
  __shared__ ushort_t Wh[OUT][KP], Wl[OUT][KP];

  const int tid = threadIdx.x;
  const int wv = tid >> 6;
  const int lane = tid & 63;
  const int wr = wv >> 1;
  const int wc = wv & 1;
  const int row0 = blockIdx.x * 64;
  const int fr = lane & 15;
  const int fg = lane >> 4;

  f32x4 acc[2][NCT];
#pragma unroll
  for (int i = 0; i < 2; ++i)
#pragma unroll
    for (int j = 0; j < NCT; ++j) acc[i][j] = (f32x4){0.f, 0.f, 0.f, 0.f};

  float4 xr[4];
  ushort4 wrh[NWLD], wrl[NWLD];

#define LOADX(kg)                                                                       \
  {                                                                                     \
    _Pragma("unroll") for (int p_ = 0; p_ < 4; ++p_) {                                  \
      int idx_ = p_ * 256 + tid;                                                        \
      xr[p_] = *reinterpret_cast<const float4*>(                                        \
          x + (size_t)(row0 + (idx_ >> 4)) * K + (kg) + (idx_ & 15) * 4);               \
    }                                                                                   \
  }
#define LOADW(kg)                                                                       \
  {                                                                                     \
    _Pragma("unroll") for (int p_ = 0; p_ < NWLD; ++p_) {                               \
      int idx_ = p_ * 256 + tid;                                                        \
      int c_ = idx_ >> 4, k4_ = idx_ & 15;                                              \
      wrh[p_] = *reinterpret_cast<const ushort4*>(WhT + (size_t)c_ * K + (kg) + k4_ * 4);\
      wrl[p_] = *reinterpret_cast<const ushort4*>(WlT + (size_t)c_ * K + (kg) + k4_ * 4);\
    }                                                                                   \
  }

  LOADX(0);
  LOADW(0);

#pragma unroll 1
  for (int k0 = 0; k0 < K; k0 += BK) {
    __syncthreads(); // previous chunk's readers done
    // store prefetched x (convert to bf16 hi/lo) and W into LDS
#pragma unroll
    for (int p = 0; p < 4; ++p) {
      int idx = p * 256 + tid;
      int r = idx >> 4, c4 = idx & 15;
      float4 v = xr[p];
      ushort4 h, l;
      h.x = f2bf(v.x); l.x = f2bf(v.x - bf2f(h.x));
      h.y = f2bf(v.y); l.y = f2bf(v.y - bf2f(h.y));
      h.z = f2bf(v.z); l.z = f2bf(v.z - bf2f(h.z));
      h.w = f2bf(v.w); l.w = f2bf(v.w - bf2f(h.w));
      *reinterpret_cast<ushort4*>(&Xh[r][c4 * 4]) = h;
      *reinterpret_cast<ushort4*>(&Xl[r][c4 * 4]) = l;
    }
#pragma unroll
    for (int p = 0; p < NWLD; ++p) {
      int idx = p * 256 + tid;
      int c = idx >> 4, k4 = idx & 15;
      *reinterpret_cast<ushort4*>(&Wh[c][k4 * 4]) = wrh[p];
      *reinterpret_cast<ushort4*>(&Wl[c][k4 * 4]) = wrl[p];
    }
    // prefetch next chunk (latency hidden under barrier + MFMA section)
    if (k0 + BK < K) {
      LOADX(k0 + BK);
      LOADW(k0 + BK);
    }
    __syncthreads();

#pragma unroll
    for (int s = 0; s < 2; ++s) {
      const int kk = s * 32 + fg * 8;
      bf16x8 ah[2], al[2];
#pragma unroll
      for (int i = 0; i < 2; ++i) {
        int r = wr * 32 + i * 16 + fr;
        ah[i] = *reinterpret_cast<const bf16x8*>(&Xh[r][kk]);
        al[i] = *reinterpret_cast<const bf16x8*>(&Xl[r][kk]);
      }
#pragma unroll
      for (int j = 0; j < NCT; ++j) {
        int c = wc * (OUT / 2) + j * 16 + fr;
        bf16x8 bh = *reinterpret_cast<const bf16x8*>(&Wh[c][kk]);
        bf16x8 bl = *reinterpret_cast<const bf16x8*>(&Wl[c][kk]);
#pragma unroll
        for (int i = 0; i < 2; ++i) {
          acc[i][j] = __builtin_amdgcn_mfma_f32_16x16x32_bf16(ah[i], bh, acc[i][j], 0, 0, 0);
          acc[i][j] = __builtin_amdgcn_mfma_f32_16x16x32_bf16(ah[i], bl, acc[i][j], 0, 0, 0);
          acc[i][j] = __builtin_amdgcn_mfma_f32_16x16x32_bf16(al[i], bh, acc[i][j], 0, 0, 0);
        }
      }
    }
  }
#undef LOADX
#undef LOADW

#pragma unroll
  for (int i = 0; i < 2; ++i) {
#pragma unroll
    for (int q = 0; q < 4; ++q) {
      int row = row0 + wr * 32 + i * 16 + fg * 4 + q;
#pragma unroll
      for (int j = 0; j < NCT; ++j) {
        int col = wc * (OUT / 2) + j * 16 + fr;
        ht[(size_t)row * OUT + col] = f2bf(acc[i][j][q]);
      }
    }
  }
}

// ---------------------------------------------------------------------------
// bf16-input MFMA GEMM (x already bf16, no split): 2 MFMAs (a*bh + a*bl).
// ---------------------------------------------------------------------------
template <int K, int OUT>
__global__ __launch_bounds__(256) void gemm_mfma_bf16in(const ushort_t* __restrict__ x,
                                                        const ushort_t* __restrict__ WhT,
                                                        const ushort_t* __restrict__ WlT,
                                                        ushort_t* __restrict__ ht, int n) {
  constexpr int BK = 64, KP = BK + 8;
  constexpr int NCT = OUT / 32;
  constexpr int NWLD = OUT * 16 / 256;
  __shared__ ushort_t Xh[64][KP];
  __shared__ ushort_t Wh[OUT][KP], Wl[OUT][KP];

  const int tid = threadIdx.x;
  const int wv = tid >> 6;
  const int lane = tid & 63;
  const int wr = wv >> 1;
  const int wc = wv & 1;
  const int row0 = blockIdx.x * 64;
  const int fr = lane & 15;
  const int fg = lane >> 4;

  f32x4 acc[2][NCT];
#pragma unroll
  for (int i = 0; i < 2; ++i)
#pragma unroll
    for (int j = 0; j < NCT; ++j) acc[i][j] = (f32x4){0.f, 0.f, 0.f, 0.f};

  ushort4 xr[4];
  ushort4 wrh[NWLD], wrl[NWLD];

#define LOADX(kg)                                                                       \
  {                                                                                     \
    _Pragma("unroll") for (int p_ = 0; p_ < 4; ++p_) {                                  \
      int idx_ = p_ * 256 + tid;                                                        \
      xr[p_] = *reinterpret_cast<const ushort4*>(                                       \
          x + (size_t)(row0 + (idx_ >> 4)) * K + (kg) + (idx_ & 15) * 4);               \
    }                                                                                   \
  }
#define LOADW(kg)                                                                       \
  {                                                                                     \
    _Pragma("unroll") for (int p_ = 0; p_ < NWLD; ++p_) {                               \
      int idx_ = p_ * 256 + tid;                                                        \
      int c_ = idx_ >> 4, k4_ = idx_ & 15;                                              \
      wrh[p_] = *reinterpret_cast<const ushort4*>(WhT + (size_t)c_ * K + (kg) + k4_ * 4);\
      wrl[p_] = *reinterpret_cast<const ushort4*>(WlT + (size_t)c_ * K + (kg) + k4_ * 4);\
    }                                                                                   \
  }

  LOADX(0);
  LOADW(0);

#pragma unroll 1
  for (int k0 = 0; k0 < K; k0 += BK) {
    __syncthreads();
#pragma unroll
    for (int p = 0; p < 4; ++p) {
      int idx = p * 256 + tid;
      *reinterpret_cast<ushort4*>(&Xh[idx >> 4][(idx & 15) * 4]) = xr[p];
    }
#pragma unroll
    for (int p = 0; p < NWLD; ++p) {
      int idx = p * 256 + tid;
      int c = idx >> 4, k4 = idx & 15;
      *reinterpret_cast<ushort4*>(&Wh[c][k4 * 4]) = wrh[p];
      *reinterpret_cast<ushort4*>(&Wl[c][k4 * 4]) = wrl[p];
    }
    if (k0 + BK < K) {
      LOADX(k0 + BK);
      LOADW(k0 + BK);
    }
    __syncthreads();

#pragma unroll
    for (int s = 0; s < 2; ++s) {
      const int kk = s * 32 + fg * 8;
      bf16x8 ah[2];
#pragma unroll
      for (int i = 0; i < 2; ++i)
        ah[i] = *reinterpret_cast<const bf16x8*>(&Xh[wr * 32 + i * 16 + fr][kk]);
#pragma unroll
      for (int j = 0; j < NCT; ++j) {
        int c = wc * (OUT / 2) + j * 16 + fr;
        bf16x8 bh = *reinterpret_cast<const bf16x8*>(&Wh[c][kk]);
        bf16x8 bl = *reinterpret_cast<const bf16x8*>(&Wl[c][kk]);
#pragma unroll
        for (int i = 0; i < 2; ++i) {
          acc[i][j] = __builtin_amdgcn_mfma_f32_16x16x32_bf16(ah[i], bh, acc[i][j], 0, 0, 0);
          acc[i][j] = __builtin_amdgcn_mfma_f32_16x16x32_bf16(ah[i], bl, acc[i][j], 0, 0, 0);
        }
      }
    }
  }
#undef LOADX
#undef LOADW

#pragma unroll
  for (int i = 0; i < 2; ++i) {
#pragma unroll
    for (int q = 0; q < 4; ++q) {
      int row = row0 + wr * 32 + i * 16 + fg * 4 + q;
#pragma unroll
      for (int j = 0; j < NCT; ++j) {
        int col = wc * (OUT / 2) + j * 16 + fr;
        ht[(size_t)row * OUT + col] = f2bf(acc[i][j][q]);
      }
    }
  }
}

// bf16 gather: 4 bf16 (8B) per lane-group slot
#define GATHB(e, acc)                                                               \
  {                                                                                 \
    float w_ = __int_as_float(e.y);                                                 \
    ushort4 h_ = *reinterpret_cast<const ushort4*>(ht + (size_t)e.x * OUT + cg * 4);\
    acc.x += w_ * bf2f(h_.x);                                                       \
    acc.y += w_ * bf2f(h_.y);                                                       \
    acc.z += w_ * bf2f(h_.z);                                                       \
    acc.w += w_ * bf2f(h_.w);                                                       \
  }

// out[v] = tanh(nd*sum + b), written bf16 (layer-1 activation feeds bf16 gemm2)
template <int OUT>
__global__ void aggregate_kernel(const ushort_t* __restrict__ ht, const int* __restrict__ row_ptr,
                                 const int2* __restrict__ csr, const float* __restrict__ norm_dst,
                                 const float* __restrict__ bias, ushort_t* __restrict__ out,
                                 int n) {
  constexpr int LPN = OUT / 4;
  constexpr int NPB = 256 / LPN;
  const int tid = threadIdx.x;
  const int cg = tid % LPN;
  const int v = blockIdx.x * NPB + tid / LPN;
  if (v >= n) return;

  const int s0 = row_ptr[v];
  const int s1 = row_ptr[v + 1];
  float4 a0 = {0, 0, 0, 0}, a1 = {0, 0, 0, 0}, a2 = {0, 0, 0, 0}, a3 = {0, 0, 0, 0};
  int i = s0;
  for (; i + 4 <= s1; i += 4) {
    int2 e0 = csr[i], e1 = csr[i + 1], e2 = csr[i + 2], e3 = csr[i + 3];
    GATHB(e0, a0);
    GATHB(e1, a1);
    GATHB(e2, a2);
    GATHB(e3, a3);
  }
  for (; i < s1; ++i) {
    int2 e = csr[i];
    GATHB(e, a0);
  }
  float nd = norm_dst[v];
  float4 b4 = *reinterpret_cast<const float4*>(bias + cg * 4);
  ushort4 r;
  r.x = f2bf(tanhf((a0.x + a1.x + a2.x + a3.x) * nd + b4.x));
  r.y = f2bf(tanhf((a0.y + a1.y + a2.y + a3.y) * nd + b4.y));
  r.z = f2bf(tanhf((a0.z + a1.z + a2.z + a3.z) * nd + b4.z));
  r.w = f2bf(tanhf((a0.w + a1.w + a2.w + a3.w) * nd + b4.w));
  *reinterpret_cast<ushort4*>(out + (size_t)v * OUT + cg * 4) = r;
}

// Layer-2 aggregate fused with layer-3 transform (norm folded into csr_w).
__global__ void aggregate2_fuse3(const ushort_t* __restrict__ ht, const int* __restrict__ row_ptr,
                                 const int2* __restrict__ csr, const float* __restrict__ norm_dst,
                                 const float* __restrict__ bias, const float* __restrict__ W3,
                                 float* __restrict__ ht3, int n) {
  constexpr int OUT = 64;
  constexpr int LPN = OUT / 4; // 16
  constexpr int NPB = 256 / LPN;
  const int tid = threadIdx.x;
  const int cg = tid % LPN;
  const int v = blockIdx.x * NPB + tid / LPN;
  if (v >= n) return;

  const int s0 = row_ptr[v];
  const int s1 = row_ptr[v + 1];
  float4 a0 = {0, 0, 0, 0}, a1 = {0, 0, 0, 0}, a2 = {0, 0, 0, 0}, a3 = {0, 0, 0, 0};
  int i = s0;
  for (; i + 4 <= s1; i += 4) {
    int2 e0 = csr[i], e1 = csr[i + 1], e2 = csr[i + 2], e3 = csr[i + 3];
    GATHB(e0, a0);
    GATHB(e1, a1);
    GATHB(e2, a2);
    GATHB(e3, a3);
  }
  for (; i < s1; ++i) {
    int2 e = csr[i];
    GATHB(e, a0);
  }
  float nd = norm_dst[v];
  float4 b4 = *reinterpret_cast<const float4*>(bias + cg * 4);
  float ox = tanhf((a0.x + a1.x + a2.x + a3.x) * nd + b4.x);
  float oy = tanhf((a0.y + a1.y + a2.y + a3.y) * nd + b4.y);
  float oz = tanhf((a0.z + a1.z + a2.z + a3.z) * nd + b4.z);
  float ow = tanhf((a0.w + a1.w + a2.w + a3.w) * nd + b4.w);
  float4 w3 = *reinterpret_cast<const float4*>(W3 + cg * 4);
  float p = ox * w3.x + oy * w3.y + oz * w3.z + ow * w3.w;
#pragma unroll
  for (int m = 1; m < 16; m <<= 1) p += __shfl_xor(p, m, 64);
  if (cg == 0) ht3[v] = p;
}

__global__ void aggregate3_kernel(const float* __restrict__ ht3, const int* __restrict__ row_ptr,
                                  const int2* __restrict__ csr, const float* __restrict__ norm_dst,
                                  const float* __restrict__ b3, float* __restrict__ out, int n) {
  int v = blockIdx.x * blockDim.x + threadIdx.x;
  if (v >= n) return;
  const int s0 = row_ptr[v];
  const int s1 = row_ptr[v + 1];
  float p0 = 0.f, p1 = 0.f, p2 = 0.f, p3 = 0.f;
  int i = s0;
  for (; i + 4 <= s1; i += 4) {
    int2 e0 = csr[i], e1 = csr[i + 1], e2 = csr[i + 2], e3 = csr[i + 3];
    p0 += __int_as_float(e0.y) * ht3[e0.x];
    p1 += __int_as_float(e1.y) * ht3[e1.x];
    p2 += __int_as_float(e2.y) * ht3[e2.x];
    p3 += __int_as_float(e3.y) * ht3[e3.x];
  }
  for (; i < s1; ++i) {
    int2 e = csr[i];
    p0 += __int_as_float(e.y) * ht3[e.x];
  }
  out[v] = (p0 + p1 + p2 + p3) * norm_dst[v] + b3[0];
}

extern "C" void kernel_launch(void* const* d_in, const int* in_sizes, int n_in,
                              void* d_out, int out_size, void* d_ws, size_t ws_size,
                              hipStream_t stream) {
  const float* b_z = (const float*)d_in[0];
  const int* src = (const int*)d_in[1];
  const int* dst = (const int*)d_in[2];
  const float* ew = (const float*)d_in[3];
  const float* W1 = (const float*)d_in[4];
  const float* b1 = (const float*)d_in[5];
  const float* W2 = (const float*)d_in[6];
  const float* b2 = (const float*)d_in[7];
  const float* W3 = (const float*)d_in[8];
  const float* b3 = (const float*)d_in[9];

  const int N = in_sizes[0] / 256; // 32768
  const int E = in_sizes[1];       // 524288
  const int N4 = N / 4;            // 8192
  const int epb = (E + NB - 1) / NB; // 2048

  char* ws = (char*)d_ws;
  size_t off = 0;
  auto alloc = [&](size_t bytes) -> void* {
    void* p = ws + off;
    off += (bytes + 255) & ~(size_t)255;
    return p;
  };

  uint32* part = (uint32*)alloc((size_t)2 * NB * N4 * 4);   // 16 MB: [src|dst][r][w]
  uint32* psum = (uint32*)alloc((size_t)2 * RSEG * N4 * 4); // 512 KB
  uchar_t* gpre = (uchar_t*)alloc((size_t)NB * N);          // 8 MB
  float* norm_src = (float*)alloc((size_t)N * 4);
  float* norm_dst = (float*)alloc((size_t)N * 4);
  int* in_deg = (int*)alloc((size_t)N * 4);
  int* row_ptr = (int*)alloc((size_t)(N + 1) * 4);
  int* block_sums = (int*)alloc(256 * 4);
  int2* csr = (int2*)alloc((size_t)E * 8);
  ushort_t* HT = (ushort_t*)alloc((size_t)N * 128 * 2);   // bf16 ht1 / ht2 (reused)
  ushort_t* ACT1 = (ushort_t*)alloc((size_t)N * 128 * 2); // bf16 layer1 activation
  float* HT3 = (float*)alloc((size_t)N * 4);
  ushort_t* WhT1 = (ushort_t*)alloc((size_t)256 * 128 * 2);
  ushort_t* WlT1 = (ushort_t*)alloc((size_t)256 * 128 * 2);
  ushort_t* WhT2 = (ushort_t*)alloc((size_t)128 * 64 * 2);
  ushort_t* WlT2 = (ushort_t*)alloc((size_t)128 * 64 * 2);

  const uint32* part_dst = part + (size_t)NB * N4;
  const int nBlocks = (N + 255) / 256; // 128
  const int wsBlocks = (256 * 128 + 128 * 64 + 1023) / 1024; // 40

  hist_wsplit_kernel<<<NB + wsBlocks, 1024, 0, stream>>>(src, dst, part, W1, W2, WhT1, WlT1,
                                                         WhT2, WlT2, E, epb);
  norm_partial<<<dim3(N4 / 256, RSEG, 2), 256, 0, stream>>>(part, psum, N4);
  norm_final<<<N4 / 256, 256, 0, stream>>>(psum, norm_src, norm_dst, in_deg, block_sums, N4);
  scan_write_goffs<<<nBlocks, 256, 0, stream>>>(in_deg, block_sums, part_dst, row_ptr, gpre, N);
  scatter_kernel<<<NB, 1024, 0, stream>>>(src, dst, ew, norm_src, row_ptr, gpre, csr, N, E, epb);

  // Layer 1: 256 -> 128, tanh (output bf16)
  gemm_mfma<256, 128><<<N / 64, 256, 0, stream>>>(b_z, WhT1, WlT1, HT, N);
  aggregate_kernel<128><<<(N + 7) / 8, 256, 0, stream>>>(HT, row_ptr, csr, norm_dst, b1, ACT1, N);
  // Layer 2: 128 -> 64 (tanh) fused with layer-3 transform (64 -> 1)
  gemm_mfma_bf16in<128, 64><<<N / 64, 256, 0, stream>>>(ACT1, WhT2, WlT2, HT, N);
  aggregate2_fuse3<<<(N + 15) / 16, 256, 0, stream>>>(HT, row_ptr, csr, norm_dst, b2, W3, HT3, N);
  // Layer 3 aggregate: 1 col, no tanh
  aggregate3_kernel<<<nBlocks, 256, 0, stream>>>(HT3, row_ptr, csr, norm_dst, b3,
                                                 (float*)d_out, N);
}

// Round 14
// 105.437 us; speedup vs baseline: 1.5951x; 1.0217x over previous
//
#include <hip/hip_runtime.h>

// ---------------------------------------------------------------------------
// GCN 3-layer forward on a static graph.
// R2-R6: tiled SGEMM, parallel scan, int2 CSR, LDS histograms/rank-scatter.
// R7-R9: f32 SGEMM structurally capped ~45us (LDS pipe vs 4 SIMDs).
// R10: bf16 split-precision MFMA GEMM: 168->141.5us.
// R11: bf16 HT gather operand: ->124us (absmax 3e-5 -> 6.1e-5).
// R12: preprocessing occupancy (NB=256, u8 gpre, 2-stage norm): ->111.5us.
// R13: gemm reg-prefetch; ACT1 bf16; norm folded into csr_w: ->107.7us.
//     CALIBRATION: absmax stayed 6.1e-5 through ACT1-bf16 -> each extra
//     bf16-rounded tensor costs only +0..3e-5 absmax (a-priori model 5-10x
//     pessimistic).
// R14: calibrated precision cuts: gemm1 drops xl*wh (2 MFMAs, Xl LDS gone ->
//     3 blocks/CU), gemm2 drops Wl (1 MFMA); fast exp-based tanh in both
//     aggregates (libm tanhf ~40cyc -> ~12cyc x 6.3M).
// ---------------------------------------------------------------------------

#define NB 256     // edge groups == hist/scatter blocks
#define NW4 8192   // N/4 packed words (N = 32768)
#define RSEG 8     // r-segments for the 2-stage partials reduction

typedef unsigned int uint32;
typedef unsigned char uchar_t;
typedef unsigned short ushort_t;
typedef __attribute__((ext_vector_type(8))) short bf16x8;
typedef __attribute__((ext_vector_type(4))) float f32x4;

__device__ inline ushort_t f2bf(float f) {
  uint32 u = __float_as_uint(f);
  u += 0x7fffu + ((u >> 16) & 1u);
  return (ushort_t)(u >> 16);
}
__device__ inline float bf2f(ushort_t h) { return __uint_as_float(((uint32)h) << 16); }

// tanh = (e^{2x}-1)/(e^{2x}+1); clamp keeps t finite, rcp approx ~1ulp.
__device__ inline float fast_tanh(float x) {
  float xc = fminf(fmaxf(x, -30.f), 30.f);
  float t = __expf(2.0f * xc);
  return (t - 1.0f) * __builtin_amdgcn_rcpf(t + 1.0f);
}

// --- hist (blocks < NB) + W pre-split (blocks >= NB) ------------------------
__global__ __launch_bounds__(1024) void hist_wsplit_kernel(
    const int* __restrict__ src, const int* __restrict__ dst, uint32* __restrict__ part,
    const float* __restrict__ W1, const float* __restrict__ W2,
    ushort_t* __restrict__ WhT1, ushort_t* __restrict__ WlT1,
    ushort_t* __restrict__ WhT2, int e, int epb) {
  const int t = threadIdx.x;
  if (blockIdx.x >= NB) {
    int i = (blockIdx.x - NB) * 1024 + t;
    if (i < 256 * 128) {
      int k = i / 128, c = i % 128;
      float f = W1[i];
      ushort_t h = f2bf(f);
      WhT1[(size_t)c * 256 + k] = h;
      WlT1[(size_t)c * 256 + k] = f2bf(f - bf2f(h));
    } else if (i < 256 * 128 + 128 * 64) {
      int j = i - 256 * 128;
      int k = j / 64, c = j % 64;
      WhT2[(size_t)c * 128 + k] = f2bf(W2[j]);
    }
    return;
  }
  __shared__ uint32 hs[NW4];
  __shared__ uint32 hd[NW4];
  for (int w = t; w < NW4; w += 1024) {
    hs[w] = 0;
    hd[w] = 0;
  }
  __syncthreads();
  const int base = blockIdx.x * epb;
  for (int k = t; k < epb; k += 1024) {
    int i = base + k;
    if (i < e) {
      int s = src[i], d = dst[i];
      atomicAdd(&hs[s >> 2], 1u << ((s & 3) * 8));
      atomicAdd(&hd[d >> 2], 1u << ((d & 3) * 8));
    }
  }
  __syncthreads();
  uint32* ps = part + (size_t)blockIdx.x * NW4;
  uint32* pd = part + (size_t)(NB + blockIdx.x) * NW4;
  for (int w = t; w < NW4; w += 1024) {
    ps[w] = hs[w];
    pd[w] = hd[w];
  }
}

// --- stage A: sum NB/RSEG r-values per word per segment ---------------------
__global__ __launch_bounds__(256) void norm_partial(const uint32* __restrict__ part,
                                                    uint32* __restrict__ psum, int n4) {
  const int w = blockIdx.x * 256 + threadIdx.x;
  const int seg = blockIdx.y;
  const int a = blockIdx.z;
  const uint32* p = part + (size_t)a * NB * n4 + (size_t)seg * (NB / RSEG) * n4 + w;
  uint32 s = 0;
#pragma unroll
  for (int r = 0; r < NB / RSEG; ++r) s += p[(size_t)r * n4];
  psum[(size_t)a * RSEG * n4 + (size_t)seg * n4 + w] = s;
}

// --- stage B: fold segments -> norms/in_deg + chunk sums --------------------
__global__ __launch_bounds__(256) void norm_final(const uint32* __restrict__ psum,
                                                  float* __restrict__ norm_src,
                                                  float* __restrict__ norm_dst,
                                                  int* __restrict__ in_deg,
                                                  int* __restrict__ block_sums, int n4) {
  const int w = blockIdx.x * 256 + threadIdx.x;
  if (w >= n4) return;
  uint32 ss = 0, sd = 0;
#pragma unroll
  for (int seg = 0; seg < RSEG; ++seg) {
    ss += psum[(size_t)seg * n4 + w];
    sd += psum[(size_t)(RSEG + seg) * n4 + w];
  }
  int idsum = 0;
#pragma unroll
  for (int j = 0; j < 4; ++j) {
    int v = w * 4 + j;
    int od = (ss >> (j * 8)) & 0xff;
    int id = (sd >> (j * 8)) & 0xff;
    norm_src[v] = 1.0f / sqrtf((float)max(od, 1));
    norm_dst[v] = 1.0f / sqrtf((float)max(id, 1));
    in_deg[v] = id;
    idsum += id;
  }
#pragma unroll
  for (int off = 32; off > 0; off >>= 1) idsum += __shfl_down(idsum, off, 64);
  if ((threadIdx.x & 63) == 0) block_sums[w >> 6] = idsum;
}

// --- chunk scan (block offset inlined) -> row_ptr + u8 group offsets --------
__global__ __launch_bounds__(256) void scan_write_goffs(const int* __restrict__ in_deg,
                                                        const int* __restrict__ block_sums,
                                                        const uint32* __restrict__ part_dst,
                                                        int* __restrict__ row_ptr,
                                                        uchar_t* __restrict__ gpre, int n) {
  __shared__ int sh[256];
  __shared__ int s_boff;
  const int t = threadIdx.x;
  const int gid = blockIdx.x * 256 + t;
  {
    int v = (t < blockIdx.x && t < 128) ? block_sums[t] : 0;
#pragma unroll
    for (int off = 32; off > 0; off >>= 1) v += __shfl_down(v, off, 64);
    if ((t & 63) == 0) sh[t >> 6] = v;
    __syncthreads();
    if (t == 0) s_boff = sh[0] + sh[1] + sh[2] + sh[3];
    __syncthreads();
  }
  int d = (gid < n) ? in_deg[gid] : 0;
  sh[t] = d;
  __syncthreads();
  for (int off = 1; off < 256; off <<= 1) {
    int v = sh[t];
    int add = (t >= off) ? sh[t - off] : 0;
    __syncthreads();
    sh[t] = v + add;
    __syncthreads();
  }
  if (gid >= n) return;
  int excl = s_boff + sh[t] - d;
  row_ptr[gid] = excl;
  if (gid == n - 1) row_ptr[n] = excl + d;
  const int w = gid >> 2;
  const int shft = (gid & 3) * 8;
  const int n4 = n >> 2;
  int cum = 0;
#pragma unroll 8
  for (int r = 0; r < NB; ++r) {
    gpre[(size_t)r * n + gid] = (uchar_t)cum;
    cum += (part_dst[(size_t)r * n4 + w] >> shft) & 0xff;
  }
}

// --- scatter: LDS rank + row_ptr + gpre; csr weight = ew * norm_src[src] ----
__global__ __launch_bounds__(1024) void scatter_kernel(const int* __restrict__ src,
                                                       const int* __restrict__ dst,
                                                       const float* __restrict__ ew,
                                                       const float* __restrict__ norm_src,
                                                       const int* __restrict__ row_ptr,
                                                       const uchar_t* __restrict__ gpre,
                                                       int2* __restrict__ csr,
                                                       int n, int e, int epb) {
  __shared__ uint32 rk[NW4];
  const int t = threadIdx.x;
  for (int w = t; w < NW4; w += 1024) rk[w] = 0;
  __syncthreads();
  const int base = blockIdx.x * epb;
  const uchar_t* gp = gpre + (size_t)blockIdx.x * n;
  for (int k = t; k < epb; k += 1024) {
    int i = base + k;
    if (i < e) {
      int s = src[i];
      int d = dst[i];
      uint32 sh = (d & 3) * 8;
      uint32 old = atomicAdd(&rk[d >> 2], 1u << sh);
      int rank = (old >> sh) & 0xff;
      int pos = row_ptr[d] + (int)gp[d] + rank;
      csr[pos] = make_int2(s, __float_as_int(ew[i] * norm_src[s]));
    }
  }
}

// ---------------------------------------------------------------------------
// MFMA GEMM, f32 input rounded to bf16-high: ht = bf16(x @ W), 2 MFMAs
// (ah*bh + ah*bl). Register-prefetch of next chunk hides cold-load latency.
// ---------------------------------------------------------------------------
template <int K, int OUT>
__global__ __launch_bounds__(256) void gemm_mfma(const float* __restrict__ x,
                                                 const ushort_t* __restrict__ WhT,
                                                 const ushort_t* __restrict__ WlT,
                                                 ushort_t* __restrict__ ht, int n) {
  constexpr int BK = 64, KP = BK + 8;
  constexpr int NCT = OUT / 32;
  constexpr int NWLD = OUT * 16 / 256;
  __shared__ ushort_t Xh[64][KP];
  __shared__ ushort_t Wh[OUT][KP], Wl[OUT][KP];

  const int tid = threadIdx.x;
  const int wv = tid >> 6;
  const int lane = tid & 63;
  const int wr = wv >> 1;
  const int wc = wv & 1;
  const int row0 = blockIdx.x * 64;
  const int fr = lane & 15;
  const int fg = lane >> 4;

  f32x4 acc[2][NCT];
#pragma unroll
  for (int i = 0; i < 2; ++i)
#pragma unroll
    for (int j = 0; j < NCT; ++j) acc[i][j] = (f32x4){0.f, 0.f, 0.f, 0.f};

  float4 xr[4];
  ushort4 wrh[NWLD], wrl[NWLD];

#define LOADX(kg)                                                                       \
  {                                                                                     \
    _Pragma("unroll") for (int p_ = 0; p_ < 4; ++p_) {                                  \
      int idx_ = p_ * 256 + tid;                                                        \
      xr[p_] = *reinterpret_cast<const float4*>(                                        \
          x + (size_t)(row0 + (idx_ >> 4)) * K + (kg) + (idx_ & 15) * 4);               \
    }                                                                                   \
  }
#define LOADW(kg)                                                                       \
  {                                                                                     \
    _Pragma("unroll") for (int p_ = 0; p_ < NWLD; ++p_) {                               \
      int idx_ = p_ * 256 + tid;                                                        \
      int c_ = idx_ >> 4, k4_ = idx_ & 15;                                              \
      wrh[p_] = *reinterpret_cast<const ushort4*>(WhT + (size_t)c_ * K + (kg) + k4_ * 4);\
      wrl[p_] = *reinterpret_cast<const ushort4*>(WlT + (size_t)c_ * K + (kg) + k4_ * 4);\
    }                                                                                   \
  }

  LOADX(0);
  LOADW(0);

#pragma unroll 1
  for (int k0 = 0; k0 < K; k0 += BK) {
    __syncthreads();
#pragma unroll
    for (int p = 0; p < 4; ++p) {
      int idx = p * 256 + tid;
      int r = idx >> 4, c4 = idx & 15;
      float4 v = xr[p];
      ushort4 h;
      h.x = f2bf(v.x);
      h.y = f2bf(v.y);
      h.z = f2bf(v.z);
      h.w = f2bf(v.w);
      *reinterpret_cast<ushort4*>(&Xh[r][c4 * 4]) = h;
    }
#pragma unroll
    for (int p = 0; p < NWLD; ++p) {
      int idx = p * 256 + tid;
      int c = idx >> 4, k4 = idx & 15;
      *reinterpret_cast<ushort4*>(&Wh[c][k4 * 4]) = wrh[p];
      *reinterpret_cast<ushort4*>(&Wl[c][k4 * 4]) = wrl[p];
    }
    if (k0 + BK < K) {
      LOADX(k0 + BK);
      LOADW(k0 + BK);
    }
    __syncthreads();

#pragma unroll
    for (int s = 0; s < 2; ++s) {
      const int kk = s * 32 + fg * 8;
      bf16x8 ah[2];
#pragma unroll
      for (int i = 0; i < 2; ++i)
        ah[i] = *reinterpret_cast<const bf16x8*>(&Xh[wr * 32 + i * 16 + fr][kk]);
#pragma unroll
      for (int j = 0; j < NCT; ++j) {
        int c = wc * (OUT / 2) + j * 16 + fr;
        bf16x8 bh = *reinterpret_cast<const bf16x8*>(&Wh[c][kk]);
        bf16x8 bl = *reinterpret_cast<const bf16x8*>(&Wl[c][kk]);
#pragma unroll
        for (int i = 0; i < 2; ++i) {
          acc[i][j] = __builtin_amdgcn_mfma_f32_16x16x32_bf16(ah[i], bh, acc[i][j], 0, 0, 0);
          acc[i][j] = __builtin_amdgcn_mfma_f32_16x16x32_bf16(ah[i], bl, acc[i][j], 0, 0, 0);
        }
      }
    }
  }
#undef LOADX
#undef LOADW

#pragma unroll
  for (int i = 0; i < 2; ++i) {
#pragma unroll
    for (int q = 0; q < 4; ++q) {
      int row = row0 + wr * 32 + i * 16 + fg * 4 + q;
#pragma unroll
      for (int j = 0; j < NCT; ++j) {
        int col = wc * (OUT / 2) + j * 16 + fr;
        ht[(size_t)row * OUT + col] = f2bf(acc[i][j][q]);
      }
    }
  }
}

// ---------------------------------------------------------------------------
// bf16-input MFMA GEMM, W bf16-high only: 1 MFMA per fragment.
// ---------------------------------------------------------------------------
template <int K, int OUT>
__global__ __launch_bounds__(256) void gemm_mfma_bf16in(const ushort_t* __restrict__ x,
                                                        const ushort_t* __restrict__ WhT,
                                                        ushort_t* __restrict__ ht, int n) {
  constexpr int BK = 64, KP = BK + 8;
  constexpr int NCT = OUT / 32;
  constexpr int NWLD = OUT * 16 / 256;
  __shared__ ushort_t Xh[64][KP];
  __shared__ ushort_t Wh[OUT][KP];

  const int tid = threadIdx.x;
  const int wv = tid >> 6;
  const int lane = tid & 63;
  const int wr = wv >> 1;
  const int wc = wv & 1;
  const int row0 = blockIdx.x * 64;
  const int fr = lane & 15;
  const int fg = lane >> 4;

  f32x4 acc[2][NCT];
#pragma unroll
  for (int i = 0; i < 2; ++i)
#pragma unroll
    for (int j = 0; j < NCT; ++j) acc[i][j] = (f32x4){0.f, 0.f, 0.f, 0.f};

  ushort4 xr[4];
  ushort4 wrh[NWLD];

#define LOADX(kg)                                                                       \
  {                                                                                     \
    _Pragma("unroll") for (int p_ = 0; p_ < 4; ++p_) {                                  \
      int idx_ = p_ * 256 + tid;                                                        \
      xr[p_] = *reinterpret_cast<const ushort4*>(                                       \
          x + (size_t)(row0 + (idx_ >> 4)) * K + (kg) + (idx_ & 15) * 4);               \
    }                                                                                   \
  }
#define LOADW(kg)                                                                       \
  {                                                                                     \
    _Pragma("unroll") for (int p_ = 0; p_ < NWLD; ++p_) {                               \
      int idx_ = p_ * 256 + tid;                                                        \
      int c_ = idx_ >> 4, k4_ = idx_ & 15;                                              \
      wrh[p_] = *reinterpret_cast<const ushort4*>(WhT + (size_t)c_ * K + (kg) + k4_ * 4);\
    }                                                                                   \
  }

  LOADX(0);
  LOADW(0);

#pragma unroll 1
  for (int k0 = 0; k0 < K; k0 += BK) {
    __syncthreads();
#pragma unroll
    for (int p = 0; p < 4; ++p) {
      int idx = p * 256 + tid;
      *reinterpret_cast<ushort4*>(&Xh[idx >> 4][(idx & 15) * 4]) = xr[p];
    }
#pragma unroll
    for (int p = 0; p < NWLD; ++p) {
      int idx = p * 256 + tid;
      *reinterpret_cast<ushort4*>(&Wh[idx >> 4][(idx & 15) * 4]) = wrh[p];
    }
    if (k0 + BK < K) {
      LOADX(k0 + BK);
      LOADW(k0 + BK);
    }
    __syncthreads();

#pragma unroll
    for (int s = 0; s < 2; ++s) {
      const int kk = s * 32 + fg * 8;
      bf16x8 ah[2];
#pragma unroll
      for (int i = 0; i < 2; ++i)
        ah[i] = *reinterpret_cast<const bf16x8*>(&Xh[wr * 32 + i * 16 + fr][kk]);
#pragma unroll
      for (int j = 0; j < NCT; ++j) {
        int c = wc * (OUT / 2) + j * 16 + fr;
        bf16x8 bh = *reinterpret_cast<const bf16x8*>(&Wh[c][kk]);
#pragma unroll
        for (int i = 0; i < 2; ++i)
          acc[i][j] = __builtin_amdgcn_mfma_f32_16x16x32_bf16(ah[i], bh, acc[i][j], 0, 0, 0);
      }
    }
  }
#undef LOADX
#undef LOADW

#pragma unroll
  for (int i = 0; i < 2; ++i) {
#pragma unroll
    for (int q = 0; q < 4; ++q) {
      int row = row0 + wr * 32 + i * 16 + fg * 4 + q;
#pragma unroll
      for (int j = 0; j < NCT; ++j) {
        int col = wc * (OUT / 2) + j * 16 + fr;
        ht[(size_t)row * OUT + col] = f2bf(acc[i][j][q]);
      }
    }
  }
}

// bf16 gather: 4 bf16 (8B) per lane-group slot
#define GATHB(e, acc)                                                               \
  {                                                                                 \
    float w_ = __int_as_float(e.y);                                                 \
    ushort4 h_ = *reinterpret_cast<const ushort4*>(ht + (size_t)e.x * OUT + cg * 4);\
    acc.x += w_ * bf2f(h_.x);                                                       \
    acc.y += w_ * bf2f(h_.y);                                                       \
    acc.z += w_ * bf2f(h_.z);                                                       \
    acc.w += w_ * bf2f(h_.w);                                                       \
  }

// out[v] = tanh(nd*sum + b), written bf16
template <int OUT>
__global__ void aggregate_kernel(const ushort_t* __restrict__ ht, const int* __restrict__ row_ptr,
                                 const int2* __restrict__ csr, const float* __restrict__ norm_dst,
                                 const float* __restrict__ bias, ushort_t* __restrict__ out,
                                 int n) {
  constexpr int LPN = OUT / 4;
  constexpr int NPB = 256 / LPN;
  const int tid = threadIdx.x;
  const int cg = tid % LPN;
  const int v = blockIdx.x * NPB + tid / LPN;
  if (v >= n) return;

  const int s0 = row_ptr[v];
  const int s1 = row_ptr[v + 1];
  float4 a0 = {0, 0, 0, 0}, a1 = {0, 0, 0, 0}, a2 = {0, 0, 0, 0}, a3 = {0, 0, 0, 0};
  int i = s0;
  for (; i + 4 <= s1; i += 4) {
    int2 e0 = csr[i], e1 = csr[i + 1], e2 = csr[i + 2], e3 = csr[i + 3];
    GATHB(e0, a0);
    GATHB(e1, a1);
    GATHB(e2, a2);
    GATHB(e3, a3);
  }
  for (; i < s1; ++i) {
    int2 e = csr[i];
    GATHB(e, a0);
  }
  float nd = norm_dst[v];
  float4 b4 = *reinterpret_cast<const float4*>(bias + cg * 4);
  ushort4 r;
  r.x = f2bf(fast_tanh((a0.x + a1.x + a2.x + a3.x) * nd + b4.x));
  r.y = f2bf(fast_tanh((a0.y + a1.y + a2.y + a3.y) * nd + b4.y));
  r.z = f2bf(fast_tanh((a0.z + a1.z + a2.z + a3.z) * nd + b4.z));
  r.w = f2bf(fast_tanh((a0.w + a1.w + a2.w + a3.w) * nd + b4.w));
  *reinterpret_cast<ushort4*>(out + (size_t)v * OUT + cg * 4) = r;
}

// Layer-2 aggregate fused with layer-3 transform (norm folded into csr_w).
__global__ void aggregate2_fuse3(const ushort_t* __restrict__ ht, const int* __restrict__ row_ptr,
                                 const int2* __restrict__ csr, const float* __restrict__ norm_dst,
                                 const float* __restrict__ bias, const float* __restrict__ W3,
                                 float* __restrict__ ht3, int n) {
  constexpr int OUT = 64;
  constexpr int LPN = OUT / 4; // 16
  constexpr int NPB = 256 / LPN;
  const int tid = threadIdx.x;
  const int cg = tid % LPN;
  const int v = blockIdx.x * NPB + tid / LPN;
  if (v >= n) return;

  const int s0 = row_ptr[v];
  const int s1 = row_ptr[v + 1];
  float4 a0 = {0, 0, 0, 0}, a1 = {0, 0, 0, 0}, a2 = {0, 0, 0, 0}, a3 = {0, 0, 0, 0};
  int i = s0;
  for (; i + 4 <= s1; i += 4) {
    int2 e0 = csr[i], e1 = csr[i + 1], e2 = csr[i + 2], e3 = csr[i + 3];
    GATHB(e0, a0);
    GATHB(e1, a1);
    GATHB(e2, a2);
    GATHB(e3, a3);
  }
  for (; i < s1; ++i) {
    int2 e = csr[i];
    GATHB(e, a0);
  }
  float nd = norm_dst[v];
  float4 b4 = *reinterpret_cast<const float4*>(bias + cg * 4);
  float ox = fast_tanh((a0.x + a1.x + a2.x + a3.x) * nd + b4.x);
  float oy = fast_tanh((a0.y + a1.y + a2.y + a3.y) * nd + b4.y);
  float oz = fast_tanh((a0.z + a1.z + a2.z + a3.z) * nd + b4.z);
  float ow = fast_tanh((a0.w + a1.w + a2.w + a3.w) * nd + b4.w);
  float4 w3 = *reinterpret_cast<const float4*>(W3 + cg * 4);
  float p = ox * w3.x + oy * w3.y + oz * w3.z + ow * w3.w;
#pragma unroll
  for (int m = 1; m < 16; m <<= 1) p += __shfl_xor(p, m, 64);
  if (cg == 0) ht3[v] = p;
}

__global__ void aggregate3_kernel(const float* __restrict__ ht3, const int* __restrict__ row_ptr,
                                  const int2* __restrict__ csr, const float* __restrict__ norm_dst,
                                  const float* __restrict__ b3, float* __restrict__ out, int n) {
  int v = blockIdx.x * blockDim.x + threadIdx.x;
  if (v >= n) return;
  const int s0 = row_ptr[v];
  const int s1 = row_ptr[v + 1];
  float p0 = 0.f, p1 = 0.f, p2 = 0.f, p3 = 0.f;
  int i = s0;
  for (; i + 4 <= s1; i += 4) {
    int2 e0 = csr[i], e1 = csr[i + 1], e2 = csr[i + 2], e3 = csr[i + 3];
    p0 += __int_as_float(e0.y) * ht3[e0.x];
    p1 += __int_as_float(e1.y) * ht3[e1.x];
    p2 += __int_as_float(e2.y) * ht3[e2.x];
    p3 += __int_as_float(e3.y) * ht3[e3.x];
  }
  for (; i < s1; ++i) {
    int2 e = csr[i];
    p0 += __int_as_float(e.y) * ht3[e.x];
  }
  out[v] = (p0 + p1 + p2 + p3) * norm_dst[v] + b3[0];
}

extern "C" void kernel_launch(void* const* d_in, const int* in_sizes, int n_in,
                              void* d_out, int out_size, void* d_ws, size_t ws_size,
                              hipStream_t stream) {
  const float* b_z = (const float*)d_in[0];
  const int* src = (const int*)d_in[1];
  const int* dst = (const int*)d_in[2];
  const float* ew = (const float*)d_in[3];
  const float* W1 = (const float*)d_in[4];
  const float* b1 = (const float*)d_in[5];
  const float* W2 = (const float*)d_in[6];
  const float* b2 = (const float*)d_in[7];
  const float* W3 = (const float*)d_in[8];
  const float* b3 = (const float*)d_in[9];

  const int N = in_sizes[0] / 256; // 32768
  const int E = in_sizes[1];       // 524288
  const int N4 = N / 4;            // 8192
  const int epb = (E + NB - 1) / NB; // 2048

  char* ws = (char*)d_ws;
  size_t off = 0;
  auto alloc = [&](size_t bytes) -> void* {
    void* p = ws + off;
    off += (bytes + 255) & ~(size_t)255;
    return p;
  };

  uint32* part = (uint32*)alloc((size_t)2 * NB * N4 * 4);   // 16 MB
  uint32* psum = (uint32*)alloc((size_t)2 * RSEG * N4 * 4); // 512 KB
  uchar_t* gpre = (uchar_t*)alloc((size_t)NB * N);          // 8 MB
  float* norm_src = (float*)alloc((size_t)N * 4);
  float* norm_dst = (float*)alloc((size_t)N * 4);
  int* in_deg = (int*)alloc((size_t)N * 4);
  int* row_ptr = (int*)alloc((size_t)(N + 1) * 4);
  int* block_sums = (int*)alloc(256 * 4);
  int2* csr = (int2*)alloc((size_t)E * 8);
  ushort_t* HT = (ushort_t*)alloc((size_t)N * 128 * 2);   // bf16 ht1 / ht2 (reused)
  ushort_t* ACT1 = (ushort_t*)alloc((size_t)N * 128 * 2); // bf16 layer1 activation
  float* HT3 = (float*)alloc((size_t)N * 4);
  ushort_t* WhT1 = (ushort_t*)alloc((size_t)256 * 128 * 2);
  ushort_t* WlT1 = (ushort_t*)alloc((size_t)256 * 128 * 2);
  ushort_t* WhT2 = (ushort_t*)alloc((size_t)128 * 64 * 2);

  const uint32* part_dst = part + (size_t)NB * N4;
  const int nBlocks = (N + 255) / 256; // 128
  const int wsBlocks = (256 * 128 + 128 * 64 + 1023) / 1024; // 40

  hist_wsplit_kernel<<<NB + wsBlocks, 1024, 0, stream>>>(src, dst, part, W1, W2, WhT1, WlT1,
                                                         WhT2, E, epb);
  norm_partial<<<dim3(N4 / 256, RSEG, 2), 256, 0, stream>>>(part, psum, N4);
  norm_final<<<N4 / 256, 256, 0, stream>>>(psum, norm_src, norm_dst, in_deg, block_sums, N4);
  scan_write_goffs<<<nBlocks, 256, 0, stream>>>(in_deg, block_sums, part_dst, row_ptr, gpre, N);
  scatter_kernel<<<NB, 1024, 0, stream>>>(src, dst, ew, norm_src, row_ptr, gpre, csr, N, E, epb);

  // Layer 1: 256 -> 128, tanh (output bf16)
  gemm_mfma<256, 128><<<N / 64, 256, 0, stream>>>(b_z, WhT1, WlT1, HT, N);
  aggregate_kernel<128><<<(N + 7) / 8, 256, 0, stream>>>(HT, row_ptr, csr, norm_dst, b1, ACT1, N);
  // Layer 2: 128 -> 64 (tanh) fused with layer-3 transform (64 -> 1)
  gemm_mfma_bf16in<128, 64><<<N / 64, 256, 0, stream>>>(ACT1, WhT2, HT, N);
  aggregate2_fuse3<<<(N + 15) / 16, 256, 0, stream>>>(HT, row_ptr, csr, norm_dst, b2, W3, HT3, N);
  // Layer 3 aggregate: 1 col, no tanh
  aggregate3_kernel<<<nBlocks, 256, 0, stream>>>(HT3, row_ptr, csr, norm_dst, b3,
                                                 (float*)d_out, N);
}